// Round 10
// baseline (285.510 us; speedup 1.0000x reference)
//
#include <hip/hip_runtime.h>
#include <stdint.h>

typedef __attribute__((ext_vector_type(4))) float          f32x4;
typedef __attribute__((ext_vector_type(8))) short          bf16x8;
typedef __attribute__((ext_vector_type(8))) unsigned short u16x8;
typedef __attribute__((ext_vector_type(4))) unsigned short u16x4;

static __device__ __forceinline__ unsigned short f2bf(float f){
  uint32_t u = __builtin_bit_cast(uint32_t, f);
  u += 0x7FFFu + ((u >> 16) & 1u);          // RNE
  return (unsigned short)(u >> 16);
}
static __device__ __forceinline__ float bf2f(unsigned short h){
  uint32_t u = ((uint32_t)h) << 16;
  return __builtin_bit_cast(float, u);
}

// ---- cvtT: x f32 [32768][768] -> x_bf (row-major bf16) AND xT[8][768][4096] -
__global__ void k_cvtT(const float* __restrict__ in, unsigned short* __restrict__ xbf,
                       unsigned short* __restrict__ xT){
  __shared__ float tl[64][65];
  const int c0 = blockIdx.x * 64, r0 = blockIdx.y * 64;   // c: e-col, r: global n-row
  const int t = threadIdx.x;
  {
    const int lr = t >> 2, lc = (t & 3) * 16;
    const f32x4* s = (const f32x4*)(in + (long)(r0 + lr) * 768 + c0 + lc);
    f32x4 v[4];
    #pragma unroll
    for (int q = 0; q < 4; q++){
      v[q] = s[q];
      #pragma unroll
      for (int j = 0; j < 4; j++) tl[lr][lc + q*4 + j] = v[q][j];
    }
    u16x8 o0, o1;
    #pragma unroll
    for (int j = 0; j < 4; j++){ o0[j] = f2bf(v[0][j]); o0[4+j] = f2bf(v[1][j]);
                                 o1[j] = f2bf(v[2][j]); o1[4+j] = f2bf(v[3][j]); }
    u16x8* d = (u16x8*)(xbf + (long)(r0 + lr) * 768 + c0 + lc);
    d[0] = o0; d[1] = o1;
  }
  __syncthreads();
  {
    const int oc = t >> 2, orr = (t & 3) * 16;
    const int b = r0 >> 12, n0 = r0 & 4095;
    u16x8 o0, o1;
    #pragma unroll
    for (int i = 0; i < 8; i++){ o0[i] = f2bf(tl[orr + i][oc]); o1[i] = f2bf(tl[orr + 8 + i][oc]); }
    u16x8* dst = (u16x8*)(xT + (long)b*3145728 + (long)(c0 + oc)*4096 + n0 + orr);
    dst[0] = o0; dst[1] = o1;
  }
}

// ---------------- tiled transpose+convert: in[R][C] f32 -> out[C][R] bf16 ----
__global__ void k_tconv(const float* __restrict__ in, unsigned short* __restrict__ out, int R, int C){
  __shared__ float tl[64][65];
  const int c0 = blockIdx.x * 64, r0 = blockIdx.y * 64;
  const int t = threadIdx.x;
  {
    const int lr = t >> 2, lc = (t & 3) * 16;
    const f32x4* s = (const f32x4*)(in + (long)(r0 + lr) * C + c0 + lc);
    #pragma unroll
    for (int q = 0; q < 4; q++){
      f32x4 v = s[q];
      #pragma unroll
      for (int j = 0; j < 4; j++) tl[lr][lc + q*4 + j] = v[j];
    }
  }
  __syncthreads();
  {
    const int oc = t >> 2, orr = (t & 3) * 16;
    u16x8 o0, o1;
    #pragma unroll
    for (int i = 0; i < 8; i++){ o0[i] = f2bf(tl[orr + i][oc]); o1[i] = f2bf(tl[orr + 8 + i][oc]); }
    u16x8* dst = (u16x8*)(out + (long)(c0 + oc) * R + r0 + orr);
    dst[0] = o0; dst[1] = o1;
  }
}

// ---- tconvQK: w_qkv cols 0..1535 -> WTr[perm(col)][768], head-pair layout ---
static __device__ __forceinline__ int mapW(int j){
  const int isK = (j >= 768);
  const int jj = j - isK * 768;
  const int h = jj / 48, c = jj - h * 48;
  return (h >> 1) * 192 + (h & 1) * 96 + isK * 48 + c;
}
__global__ void k_tconvQK(const float* __restrict__ in, unsigned short* __restrict__ out){
  __shared__ float tl[64][65];
  const int c0 = blockIdx.x * 64, r0 = blockIdx.y * 64;
  const int t = threadIdx.x;
  {
    const int lr = t >> 2, lc = (t & 3) * 16;
    const f32x4* s = (const f32x4*)(in + (long)(r0 + lr) * 2304 + c0 + lc);
    #pragma unroll
    for (int q = 0; q < 4; q++){
      f32x4 v = s[q];
      #pragma unroll
      for (int j = 0; j < 4; j++) tl[lr][lc + q*4 + j] = v[j];
    }
  }
  __syncthreads();
  {
    const int oc = t >> 2, orr = (t & 3) * 16;
    u16x8 o0, o1;
    #pragma unroll
    for (int i = 0; i < 8; i++){ o0[i] = f2bf(tl[orr + i][oc]); o1[i] = f2bf(tl[orr + 8 + i][oc]); }
    u16x8* dst = (u16x8*)(out + (long)mapW(c0 + oc) * 768 + r0 + orr);
    dst[0] = o0; dst[1] = o1;
  }
}

// ------- strided cvt: WvB[e][hd] = bf16(w_qkv[e][1536+hd]), 768x768 ---------
__global__ void k_cvtwv(const float* __restrict__ w, unsigned short* __restrict__ out){
  const long idx = ((long)blockIdx.x * blockDim.x + threadIdx.x) * 8;
  const int e = (int)(idx / 768), hd = (int)(idx - (long)e * 768);
  const float* s = w + (long)e * 2304 + 1536 + hd;
  f32x4 a = *(const f32x4*)s, b = *(const f32x4*)(s + 4);
  u16x8 o;
  #pragma unroll
  for (int j = 0; j < 4; j++){ o[j] = f2bf(a[j]); o[4+j] = f2bf(b[j]); }
  *(u16x8*)(out + idx) = o;
}

// ===================== shared GEMM machinery (BK=32, ring-3) ================
// Swizzle: LDS chunk c of row r holds global k-chunk (c ^ ((r>>1)&3)).
static __device__ __forceinline__ bf16x8 ldfrag(const char* slot, int row, int ko){
  const int k2 = (ko ^ (row >> 1)) & 3;
  return *(const bf16x8*)(slot + row*64 + k2*16);
}

#define GLL(SRC, DST) __builtin_amdgcn_global_load_lds(                         \
    (const __attribute__((address_space(1))) unsigned int*)(SRC),               \
    (__attribute__((address_space(3))) unsigned int*)(DST), 16, 0, 0)

// 512-thread stagers (pitch 768), for k_gemmP
static __device__ __forceinline__ void stageA512(const unsigned short* __restrict__ G, int row0, int ke,
                                                 char* slot, int t){
  const int r  = t >> 2;
  const int k2 = (t & 3) ^ ((r >> 1) & 3);
  GLL((const char*)(G + (long)(row0 + r) * 768 + ke + k2 * 8), slot + (t & 0x1C0) * 16);
}
static __device__ __forceinline__ void stageB512(const unsigned short* __restrict__ G, int row0, int ke,
                                                 char* slot, int t){
  #pragma unroll
  for (int l = 0; l < 2; l++){
    const int r  = l*128 + (t >> 2);
    const int k2 = (t & 3) ^ ((r >> 1) & 3);
    GLL((const char*)(G + (long)(row0 + r) * 768 + ke + k2 * 8), slot + l*8192 + (t & 0x1C0) * 16);
  }
}

// 256-thread stagers with runtime pitch, for k_bt (A: 64 rows, B: 128 rows)
static __device__ __forceinline__ void stA64(const unsigned short* __restrict__ G, int row0, int ke,
                                             int pitch, char* slot, int t){
  const int r  = t >> 2;
  const int k2 = (t & 3) ^ ((r >> 1) & 3);
  GLL((const char*)(G + (long)(row0 + r) * pitch + ke + k2 * 8), slot + (t & 0xC0) * 16);
}
static __device__ __forceinline__ void stB128(const unsigned short* __restrict__ G, int row0, int ke,
                                              int pitch, char* slot, int t){
  #pragma unroll
  for (int l = 0; l < 2; l++){
    const int r  = l*64 + (t >> 2);
    const int k2 = (t & 3) ^ ((r >> 1) & 3);
    GLL((const char*)(G + (long)(row0 + r) * pitch + ke + k2 * 8), slot + l*4096 + (t & 0xC0) * 16);
  }
}

#define VM0 asm volatile("s_waitcnt vmcnt(0)" ::: "memory")
#define VM3 asm volatile("s_waitcnt vmcnt(3)" ::: "memory")

// 8-wave phase (k_gemmP): af[4], bq[4], 16 MFMA
#define PHASE1(CUR, STAGE_STMT, WAIT_STMT) do {                                \
    bf16x8 af[4], bq[4];                                                       \
    _Pragma("unroll")                                                          \
    for (int ni = 0; ni < 4; ni++)                                             \
      bq[ni] = ldfrag(sB[CUR], wn*64 + ni*16 + arow, ko);                      \
    _Pragma("unroll")                                                          \
    for (int mi = 0; mi < 4; mi++)                                             \
      af[mi] = ldfrag(sA[CUR], wm64 + mi*16 + arow, ko);                       \
    __builtin_amdgcn_s_barrier();                                              \
    __builtin_amdgcn_s_setprio(1);                                             \
    _Pragma("unroll")                                                          \
    for (int mi = 0; mi < 4; mi++)                                             \
      _Pragma("unroll")                                                        \
      for (int ni = 0; ni < 4; ni++)                                           \
        acc[mi][ni] = __builtin_amdgcn_mfma_f32_16x16x32_bf16(                 \
            af[mi], bq[ni], acc[mi][ni], 0, 0, 0);                             \
    __builtin_amdgcn_s_setprio(0);                                             \
    STAGE_STMT;                                                                \
    WAIT_STMT;                                                                 \
    __builtin_amdgcn_s_barrier();                                              \
  } while(0)

// 4-wave phase (k_bt): af[2], bq[4], 8 MFMA
#define PH_BT(CUR, STAGE_STMT, WAIT_STMT) do {                                 \
    bf16x8 af[2], bq[4];                                                       \
    _Pragma("unroll")                                                          \
    for (int ni = 0; ni < 4; ni++)                                             \
      bq[ni] = ldfrag(sB[CUR], wn*64 + ni*16 + arow, ko);                      \
    _Pragma("unroll")                                                          \
    for (int mi = 0; mi < 2; mi++)                                             \
      af[mi] = ldfrag(sA[CUR], wm*32 + mi*16 + arow, ko);                      \
    __builtin_amdgcn_s_barrier();                                              \
    __builtin_amdgcn_s_setprio(1);                                             \
    _Pragma("unroll")                                                          \
    for (int mi = 0; mi < 2; mi++)                                             \
      _Pragma("unroll")                                                        \
      for (int ni = 0; ni < 4; ni++)                                           \
        acc[mi][ni] = __builtin_amdgcn_mfma_f32_16x16x32_bf16(                 \
            af[mi], bq[ni], acc[mi][ni], 0, 0, 0);                             \
    __builtin_amdgcn_s_setprio(0);                                             \
    STAGE_STMT;                                                                \
    WAIT_STMT;                                                                 \
    __builtin_amdgcn_s_barrier();                                              \
  } while(0)

// ====== k_bt<NKT>: batched BM=64 x BN=128 GEMM, transposed bf16 store =======
// OUT[b][jc][mrow] (pitch 768) = sum_k A[b][m0+mr][k] * B[b][j0+jc][k].
// gram:  A=B=xT (pitch 4096, NKT=128) -> G[b][e2][e1]
// gemmT: A=G (pitch 768, NKT=24), B=WTr (shared) -> Tt[b][cr][e2]
template<int NKT>
__global__ __launch_bounds__(256, 4)
void k_bt(const unsigned short* __restrict__ A, long Abstride, int Apitch,
          const unsigned short* __restrict__ B, long Bbstride, int Bpitch,
          unsigned short* __restrict__ OUT, long Obstride, int NJT)
{
  __shared__ __attribute__((aligned(16))) char lds[36864];
  const int o = blockIdx.x;
  const int b = o & 7;                       // per-XCD batch (grid = 8 * per-batch)
  const int rem = o >> 3;
  const int mt = rem / NJT, jt = rem - mt * NJT;
  const int m0 = mt * 64, j0 = jt * 128;
  const int t = threadIdx.x, lane = t & 63, w = t >> 6;   // 4 waves
  const int wm = w >> 1, wn = w & 1;
  const int arow = lane & 15, ko = lane >> 4;
  const unsigned short* Ab = A + (long)b * Abstride;
  const unsigned short* Bb = B + (long)b * Bbstride;
  unsigned short* Ob = OUT + (long)b * Obstride;

  char* const sA[3] = {lds,          lds + 4096,          lds + 8192};
  char* const sB[3] = {lds + 12288,  lds + 12288 + 8192,  lds + 12288 + 16384};

  f32x4 acc[2][4] = {};

  // prologue: tiles 0,1
  stA64(Ab, m0, 0,  Apitch, sA[0], t);  stB128(Bb, j0, 0,  Bpitch, sB[0], t);
  stA64(Ab, m0, 32, Apitch, sA[1], t);  stB128(Bb, j0, 32, Bpitch, sB[1], t);
  VM3;
  __builtin_amdgcn_s_barrier();

  constexpr int F = (NKT - 2) / 3;
  #pragma unroll 1
  for (int g = 0; g < F; ++g){
    const int kb = g * 96;
    PH_BT(0, { stA64(Ab, m0, kb+64,  Apitch, sA[2], t); stB128(Bb, j0, kb+64,  Bpitch, sB[2], t); }, VM3);
    PH_BT(1, { stA64(Ab, m0, kb+96,  Apitch, sA[0], t); stB128(Bb, j0, kb+96,  Bpitch, sB[0], t); }, VM3);
    PH_BT(2, { stA64(Ab, m0, kb+128, Apitch, sA[1], t); stB128(Bb, j0, kb+128, Bpitch, sB[1], t); }, VM3);
  }
  // tail: phases p = 3F .. NKT-1 (2 or 3 of them, fully unrolled)
  #pragma unroll
  for (int p = 3*F; p < NKT; ++p){
    const int cur = p % 3;
    if (p + 2 < NKT){
      const int ke = (p + 2) * 32, sl = (p + 2) % 3;
      PH_BT(cur, { stA64(Ab, m0, ke, Apitch, sA[sl], t); stB128(Bb, j0, ke, Bpitch, sB[sl], t); }, VM3);
    } else if (p == NKT - 2){
      PH_BT(cur, { ; }, VM0);
    } else {
      PH_BT(cur, { ; }, ;);
    }
  }

  // transposed bf16 store: OUT[b][jc][m0 + e], u16x4 along m (4 regs)
  #pragma unroll
  for (int mi = 0; mi < 2; mi++){
    #pragma unroll
    for (int ni = 0; ni < 4; ni++){
      const int jc = j0 + wn*64 + ni*16 + (lane & 15);
      const int mr = m0 + wm*32 + mi*16 + (lane >> 4)*4;
      u16x4 pk;
      #pragma unroll
      for (int r = 0; r < 4; r++) pk[r] = f2bf(acc[mi][ni][r]);
      *(u16x4*)(Ob + (long)jc*768 + mr) = pk;
    }
  }
}

// ====== k_gemmP: x_bf @ WcombT_b (batched), BM=128 BN=256 (r7 structure) ====
__global__ __launch_bounds__(512, 4)
void k_gemmP(const unsigned short* __restrict__ A, const unsigned short* __restrict__ BT,
             float* __restrict__ OUTF, const float* __restrict__ bias)
{
  __shared__ __attribute__((aligned(16))) char lds[73728];
  const int o  = blockIdx.x;
  const int wg = (o & 7) * 96 + (o >> 3);                  // 768 wgs
  const int jt = wg % 3, mt = wg / 3;
  const int m0 = mt * 128, j0 = jt * 256;
  const int t = threadIdx.x, lane = t & 63, w = t >> 6;
  const int wm = w >> 2, wn = w & 3;
  const int wm64 = wm * 64;
  const int arow = lane & 15, ko = lane >> 4;
  const unsigned short* BTb = BT + ((long)(m0 >> 12)) * 589824;

  char* const sA[3] = {lds,          lds + 8192,          lds + 16384};
  char* const sB[3] = {lds + 24576,  lds + 24576 + 16384, lds + 24576 + 32768};

  f32x4 acc[4][4] = {};

  stageA512(A, m0, 0,  sA[0], t);  stageB512(BTb, j0, 0,  sB[0], t);
  stageA512(A, m0, 32, sA[1], t);  stageB512(BTb, j0, 32, sB[1], t);
  VM3;
  __builtin_amdgcn_s_barrier();

  #pragma unroll 1
  for (int g = 0; g < 7; ++g){
    const int kb = g * 96;
    PHASE1(0, { stageA512(A, m0, kb+64,  sA[2], t); stageB512(BTb, j0, kb+64,  sB[2], t); }, VM3);
    PHASE1(1, { stageA512(A, m0, kb+96,  sA[0], t); stageB512(BTb, j0, kb+96,  sB[0], t); }, VM3);
    PHASE1(2, { stageA512(A, m0, kb+128, sA[1], t); stageB512(BTb, j0, kb+128, sB[1], t); }, VM3);
  }
  PHASE1(0, { stageA512(A, m0, 736, sA[2], t); stageB512(BTb, j0, 736, sB[2], t); }, VM3);
  PHASE1(1, { ; }, VM0);
  PHASE1(2, { ; }, ;);

  #pragma unroll
  for (int mi = 0; mi < 4; mi++){
    #pragma unroll
    for (int ni = 0; ni < 4; ni++){
      const int jc = j0 + wn*64 + ni*16 + (lane & 15);
      const float bv = bias[jc];
      const long mr = (long)m0 + wm64 + mi*16 + (lane >> 4)*4;
      #pragma unroll
      for (int r = 0; r < 4; r++) OUTF[(mr + r) * 768 + jc] = acc[mi][ni][r] + bv;
    }
  }
}

// ====== k_smax: per (b,h): S = Tq · WkT (MFMA), norms from diagonals, softmax
__global__ void k_smax(const unsigned short* __restrict__ Tt, const unsigned short* __restrict__ WTr,
                       const float* __restrict__ temp, unsigned short* __restrict__ attnT)
{
  __shared__ float Sl[48][52];
  __shared__ float invk_s[48];
  const int bh = blockIdx.x, b = bh >> 4, h = bh & 15;
  const int rowq = (h >> 1) * 192 + (h & 1) * 96, rowk = rowq + 48;
  const unsigned short* Tb = Tt + (long)b * 1179648;
  const int lane = threadIdx.x;   // 64 = 1 wave
  const int arow = lane & 15, ko = lane >> 4;

  f32x4 acc[3][3] = {};
  for (int kt = 0; kt < 768; kt += 32){
    bf16x8 af[3], bfr[3];
    #pragma unroll
    for (int ci = 0; ci < 3; ci++)
      af[ci]  = *(const bf16x8*)(Tb + (long)(rowq + ci*16 + arow)*768 + kt + ko*8);
    #pragma unroll
    for (int di = 0; di < 3; di++)
      bfr[di] = *(const bf16x8*)(WTr + (long)(rowk + di*16 + arow)*768 + kt + ko*8);
    #pragma unroll
    for (int ci = 0; ci < 3; ci++)
      #pragma unroll
      for (int di = 0; di < 3; di++)
        acc[ci][di] = __builtin_amdgcn_mfma_f32_16x16x32_bf16(af[ci], bfr[di], acc[ci][di], 0, 0, 0);
  }
  #pragma unroll
  for (int ci = 0; ci < 3; ci++)
    #pragma unroll
    for (int di = 0; di < 3; di++)
      #pragma unroll
      for (int r = 0; r < 4; r++)
        Sl[ci*16 + ko*4 + r][di*16 + arow] = acc[ci][di][r];

  float dq = 0.f;
  if (lane < 48){
    const unsigned short* tq = Tb  + (long)(rowq + lane)*768;
    const unsigned short* wq = WTr + (long)(rowq + lane)*768;
    const unsigned short* tk = Tb  + (long)(rowk + lane)*768;
    const unsigned short* wk = WTr + (long)(rowk + lane)*768;
    float dk = 0.f;
    for (int e = 0; e < 768; e += 8){
      bf16x8 a = *(const bf16x8*)(tq + e), bq_ = *(const bf16x8*)(wq + e);
      bf16x8 c = *(const bf16x8*)(tk + e), bk_ = *(const bf16x8*)(wk + e);
      #pragma unroll
      for (int j = 0; j < 8; j++){
        dq += bf2f(((u16x8)a)[j]) * bf2f(((u16x8)bq_)[j]);
        dk += bf2f(((u16x8)c)[j]) * bf2f(((u16x8)bk_)[j]);
      }
    }
    invk_s[lane] = 1.0f / fmaxf(sqrtf(dk), 1e-12f);
  }
  __syncthreads();
  if (lane < 48){
    const int c = lane;
    const float scq = temp[h] / fmaxf(sqrtf(dq), 1e-12f);
    float row[48];
    #pragma unroll
    for (int d = 0; d < 48; d++) row[d] = Sl[c][d] * scq * invk_s[d];
    float mx = -1e30f;
    #pragma unroll
    for (int d = 0; d < 48; d++) mx = fmaxf(mx, row[d]);
    float s = 0.f;
    #pragma unroll
    for (int d = 0; d < 48; d++){ row[d] = expf(row[d] - mx); s += row[d]; }
    const float inv = 1.0f / s;
    unsigned short* ob = attnT + (long)bh * 48 * 64;
    #pragma unroll
    for (int d = 0; d < 48; d++) ob[d*64 + c] = f2bf(row[d] * inv);
    u16x8 z = {};
    *(u16x8*)(ob + c*64 + 48) = z;
    *(u16x8*)(ob + c*64 + 56) = z;
  }
}

// --- WmodT[b][j][h*48+d] = sum_c attnT[bh][d][c] * WpT[j][h*48+c] (MFMA) -----
__global__ __launch_bounds__(256)
void k_wmod2(const unsigned short* __restrict__ WpT, const unsigned short* __restrict__ attnT,
             unsigned short* __restrict__ WmodT)
{
  const int j0 = blockIdx.x * 256, h = blockIdx.y, b = blockIdx.z;
  const int t = threadIdx.x, lane = t & 63, w = t >> 6;
  const unsigned short* wp = WpT + h * 48;
  const unsigned short* ab = attnT + ((long)(b*16 + h)) * 48 * 64;
  f32x4 acc[4][3] = {};
  #pragma unroll
  for (int kt = 0; kt < 64; kt += 32){
    bf16x8 bfr[3];
    #pragma unroll
    for (int ni = 0; ni < 3; ni++)
      bfr[ni] = *(const bf16x8*)(ab + (ni*16 + (lane & 15))*64 + kt + (lane >> 4)*8);
    #pragma unroll
    for (int mi = 0; mi < 4; mi++){
      const int j = j0 + w*64 + mi*16 + (lane & 15);
      bf16x8 a = *(const bf16x8*)(wp + (long)j*768 + kt + (lane >> 4)*8);
      #pragma unroll
      for (int ni = 0; ni < 3; ni++)
        acc[mi][ni] = __builtin_amdgcn_mfma_f32_16x16x32_bf16(a, bfr[ni], acc[mi][ni], 0, 0, 0);
    }
  }
  #pragma unroll
  for (int mi = 0; mi < 4; mi++)
    #pragma unroll
    for (int ni = 0; ni < 3; ni++)
      #pragma unroll
      for (int r = 0; r < 4; r++){
        const int j = j0 + w*64 + mi*16 + (lane >> 4)*4 + r;
        const int d = ni*16 + (lane & 15);
        WmodT[(long)b*589824 + (long)j*768 + h*48 + d] = f2bf(acc[mi][ni][r]);
      }
}

// --- WcombT[6144 rows=b*768+j][768 e] = WmodT[row][hd] @ WvB[e][hd] (128² tile)
__global__ __launch_bounds__(256)
void k_comb(const unsigned short* __restrict__ A, const unsigned short* __restrict__ BT,
            unsigned short* __restrict__ OUT)
{
  __shared__ unsigned short As[128 * 32];
  __shared__ unsigned short Bs[128 * 32];
  const int m0 = blockIdx.y * 128;
  const int j0 = blockIdx.x * 128;
  const int t = threadIdx.x;
  const int lane = t & 63;
  const int w = t >> 6, wm = w >> 1, wn = w & 1;

  f32x4 acc[4][4] = {};

  for (int kt = 0; kt < 768; kt += 32){
    if (kt) __syncthreads();
    #pragma unroll
    for (int i = 0; i < 2; i++){
      const char* ga = (const char*)A  + (long)(m0 + i*64 + (t >> 2)) * 1536 + kt*2 + (t & 3) * 16;
      const char* gb = (const char*)BT + (long)(j0 + i*64 + (t >> 2)) * 1536 + kt*2 + (t & 3) * 16;
      char* la = (char*)As + i*4096 + (t & 0xC0) * 16;
      char* lb = (char*)Bs + i*4096 + (t & 0xC0) * 16;
      GLL(ga, la);
      GLL(gb, lb);
    }
    __syncthreads();
    bf16x8 af[4], bfr[4];
    #pragma unroll
    for (int mi = 0; mi < 4; mi++)
      af[mi]  = *(const bf16x8*)&As[(wm*64 + mi*16 + (lane & 15)) * 32 + (lane >> 4) * 8];
    #pragma unroll
    for (int ni = 0; ni < 4; ni++)
      bfr[ni] = *(const bf16x8*)&Bs[(wn*64 + ni*16 + (lane & 15)) * 32 + (lane >> 4) * 8];
    #pragma unroll
    for (int mi = 0; mi < 4; mi++)
      #pragma unroll
      for (int ni = 0; ni < 4; ni++)
        acc[mi][ni] = __builtin_amdgcn_mfma_f32_16x16x32_bf16(af[mi], bfr[ni], acc[mi][ni], 0, 0, 0);
  }

  #pragma unroll
  for (int mi = 0; mi < 4; mi++)
    #pragma unroll
    for (int ni = 0; ni < 4; ni++){
      const int jc = j0 + wn*64 + ni*16 + (lane & 15);
      const long mr = (long)m0 + wm*64 + mi*16 + (lane >> 4) * 4;
      #pragma unroll
      for (int r = 0; r < 4; r++) OUT[(mr + r) * 768 + jc] = f2bf(acc[mi][ni][r]);
    }
}

extern "C" void kernel_launch(void* const* d_in, const int* in_sizes, int n_in,
                              void* d_out, int out_size, void* d_ws, size_t ws_size,
                              hipStream_t stream)
{
  (void)in_sizes; (void)n_in; (void)out_size; (void)ws_size;
  const float* x      = (const float*)d_in[0];
  const float* w_qkv  = (const float*)d_in[1];
  const float* temp   = (const float*)d_in[2];
  const float* w_proj = (const float*)d_in[3];
  const float* b_proj = (const float*)d_in[4];
  float* outF = (float*)d_out;

  char* ws = (char*)d_ws;
  size_t off = 0;
  auto alloc = [&](size_t bytes)->char*{ char* p = ws + off; off += (bytes + 255) & ~(size_t)255; return p; };

  unsigned short* x_bf  = (unsigned short*)alloc(50331648);           // [32768][768] bf16
  unsigned short* xT    = (unsigned short*)alloc(50331648);           // [8][768][4096] bf16
  unsigned short* WTr   = (unsigned short*)alloc(2359296);            // [1536][768] head-pair layout
  unsigned short* WpT   = (unsigned short*)alloc(1179648);            // [768][768] bf16
  unsigned short* WvB   = (unsigned short*)alloc(1179648);            // [768 e][768 hd] bf16
  unsigned short* G     = (unsigned short*)alloc(9437184);            // [8][768 e2][768 e1] bf16
  unsigned short* Tt    = (unsigned short*)alloc(18874368);           // [8][1536 cr][768 e2] bf16
  unsigned short* attnT = (unsigned short*)alloc(786432);             // [128][48 d][64 c] bf16
  unsigned short* WmodT = (unsigned short*)alloc(9437184);            // [8][768 j][768 hd] bf16
  unsigned short* WcombT= (unsigned short*)alloc(9437184);            // [8][768 j][768 e] bf16

  k_cvtT<<<dim3(12, 512), 256, 0, stream>>>(x, x_bf, xT);
  k_tconvQK<<<dim3(24, 12), 256, 0, stream>>>(w_qkv, WTr);
  k_tconv<<<dim3(12, 12), 256, 0, stream>>>(w_proj, WpT, 768, 768);
  k_cvtwv<<<288, 256, 0, stream>>>(w_qkv, WvB);
  // G_b = xT_b @ xT_b^T  (transposed store valid by symmetry; each loc written once)
  k_bt<128><<<576, 256, 0, stream>>>(xT, 3145728L, 4096, xT, 3145728L, 4096, G, 589824L, 6);
  // Tt[b][cr][e2] = (G_b @ WTr^T)^T
  k_bt<24><<<1152, 256, 0, stream>>>(G, 589824L, 768, WTr, 0L, 768, Tt, 1179648L, 12);
  k_smax<<<128, 64, 0, stream>>>(Tt, WTr, temp, attnT);
  k_wmod2<<<dim3(3, 16, 8), 256, 0, stream>>>(WpT, attnT, WmodT);
  k_comb<<<dim3(6, 48), 256, 0, stream>>>(WmodT, WvB, WcombT);
  k_gemmP<<<768, 512, 0, stream>>>(x_bf, WcombT, outF, b_proj);
}

// Round 11
// 241.300 us; speedup vs baseline: 1.1832x; 1.1832x over previous
//
#include <hip/hip_runtime.h>
#include <stdint.h>

typedef __attribute__((ext_vector_type(4))) float          f32x4;
typedef __attribute__((ext_vector_type(8))) short          bf16x8;
typedef __attribute__((ext_vector_type(8))) unsigned short u16x8;
typedef __attribute__((ext_vector_type(4))) unsigned short u16x4;

static __device__ __forceinline__ unsigned short f2bf(float f){
  uint32_t u = __builtin_bit_cast(uint32_t, f);
  u += 0x7FFFu + ((u >> 16) & 1u);          // RNE
  return (unsigned short)(u >> 16);
}
static __device__ __forceinline__ float bf2f(unsigned short h){
  uint32_t u = ((uint32_t)h) << 16;
  return __builtin_bit_cast(float, u);
}

#define GLL(SRC, DST) __builtin_amdgcn_global_load_lds(                         \
    (const __attribute__((address_space(1))) unsigned int*)(SRC),               \
    (__attribute__((address_space(3))) unsigned int*)(DST), 16, 0, 0)

// ---------------- elementwise convert f32 -> bf16 (8/thread) ----------------
__global__ void k_cvt(const float* __restrict__ in, unsigned short* __restrict__ out, long n){
  long i = ((long)blockIdx.x * blockDim.x + threadIdx.x) * 8;
  if (i >= n) return;
  const f32x4* p = (const f32x4*)(in + i);
  f32x4 a = p[0], b = p[1];
  u16x8 o;
  #pragma unroll
  for (int j = 0; j < 4; j++){ o[j] = f2bf(a[j]); o[4+j] = f2bf(b[j]); }
  *(u16x8*)(out + i) = o;
}

// ---------------- tiled transpose+convert: in[R][C] f32 -> out[C][R] bf16 ----
__global__ void k_tconv(const float* __restrict__ in, unsigned short* __restrict__ out, int R, int C){
  __shared__ float tl[64][65];
  const int c0 = blockIdx.x * 64, r0 = blockIdx.y * 64;
  const int t = threadIdx.x;
  {
    const int lr = t >> 2, lc = (t & 3) * 16;
    const f32x4* s = (const f32x4*)(in + (long)(r0 + lr) * C + c0 + lc);
    #pragma unroll
    for (int q = 0; q < 4; q++){
      f32x4 v = s[q];
      #pragma unroll
      for (int j = 0; j < 4; j++) tl[lr][lc + q*4 + j] = v[j];
    }
  }
  __syncthreads();
  {
    const int oc = t >> 2, orr = (t & 3) * 16;
    u16x8 o0, o1;
    #pragma unroll
    for (int i = 0; i < 8; i++){ o0[i] = f2bf(tl[orr + i][oc]); o1[i] = f2bf(tl[orr + 8 + i][oc]); }
    u16x8* dst = (u16x8*)(out + (long)(c0 + oc) * R + r0 + orr);
    dst[0] = o0; dst[1] = o1;
  }
}

// ------- strided cvt: WvB[e][hd] = bf16(w_qkv[e][1536+hd]), 768x768 ---------
__global__ void k_cvtwv(const float* __restrict__ w, unsigned short* __restrict__ out){
  const long idx = ((long)blockIdx.x * blockDim.x + threadIdx.x) * 8;
  const int e = (int)(idx / 768), hd = (int)(idx - (long)e * 768);
  const float* s = w + (long)e * 2304 + 1536 + hd;
  f32x4 a = *(const f32x4*)s, b = *(const f32x4*)(s + 4);
  u16x8 o;
  #pragma unroll
  for (int j = 0; j < 4; j++){ o[j] = f2bf(a[j]); o[4+j] = f2bf(b[j]); }
  *(u16x8*)(out + idx) = o;
}

// ===================== shared fragment read (conflict-free swizzle) =========
// 64B K32 rows; LDS chunk c of row r holds global k-chunk (c ^ ((r>>1)&3)).
// Verified 0 bank conflicts (r10).
static __device__ __forceinline__ bf16x8 ldfrag(const char* slot, int row, int ko){
  const int k2 = (ko ^ (row >> 1)) & 3;
  return *(const bf16x8*)(slot + row*64 + k2*16);
}

// ========== k_gemm256: 256x256 8-phase counted-vmcnt (r2 schedule + T2) =====
// BK=64 as 2 K32 slots/operand/buffer; 8 waves (2M x 4N), wave 128x64.
// Phase: reads; bar; setprio; 16 MFMA; setprio; stage; [vmcnt(6) ph4/8]; bar.
static __device__ __forceinline__ void stg256(const unsigned short* __restrict__ G, int row0, int ke,
                                              char* lds_slot, int t){
  #pragma unroll
  for (int l = 0; l < 2; l++){
    const int r  = l*128 + (t >> 2);
    const int k2 = (t & 3) ^ ((r >> 1) & 3);
    GLL((const char*)(G + (long)(row0 + r) * 768 + ke + k2 * 8),
        lds_slot + l*8192 + (t & 0x1C0) * 16);
  }
}

#define PHASE(BUF, KK, MH, STAGE_STMT, WAIT_STMT) do {                         \
    bf16x8 af[4];                                                              \
    if (MH == 0) {                                                             \
      _Pragma("unroll")                                                        \
      for (int ni = 0; ni < 4; ni++)                                           \
        bq[ni] = ldfrag(sB[BUF][KK], wn*64 + ni*16 + arow, ko);                \
    }                                                                          \
    _Pragma("unroll")                                                          \
    for (int mi = 0; mi < 4; mi++)                                             \
      af[mi] = ldfrag(sA[BUF][KK], wm*128 + MH*64 + mi*16 + arow, ko);         \
    __builtin_amdgcn_s_barrier();                                              \
    __builtin_amdgcn_s_setprio(1);                                             \
    _Pragma("unroll")                                                          \
    for (int mi = 0; mi < 4; mi++)                                             \
      _Pragma("unroll")                                                        \
      for (int ni = 0; ni < 4; ni++)                                           \
        acc[MH*4+mi][ni] = __builtin_amdgcn_mfma_f32_16x16x32_bf16(            \
            af[mi], bq[ni], acc[MH*4+mi][ni], 0, 0, 0);                        \
    __builtin_amdgcn_s_setprio(0);                                             \
    STAGE_STMT;                                                                \
    WAIT_STMT;                                                                 \
    __builtin_amdgcn_s_barrier();                                              \
  } while(0)

// A=x_bf[32768][768], BT=WT[1536 q||k][768] -> QT/KT (transposed) + nrmp
__global__ __launch_bounds__(512, 2)
void k_gemm256(const unsigned short* __restrict__ A, const unsigned short* __restrict__ BT,
               unsigned short* __restrict__ QT, unsigned short* __restrict__ KT,
               float* __restrict__ nrmp)
{
  __shared__ __attribute__((aligned(16))) char lds[131072];
  const int o  = blockIdx.x;
  const int wg = (o & 7) * 96 + (o >> 3);          // bijective XCD swizzle, 768 wgs
  const int jt = wg % 6, mt = wg / 6;
  const int m0 = mt * 256, j0 = jt * 256;
  const int t = threadIdx.x, lane = t & 63, w = t >> 6;
  const int wm = w >> 2, wn = w & 3;
  const int arow = lane & 15, ko = lane >> 4;

  char* const sA[2][2] = {{lds,           lds + 16384},
                          {lds + 65536,   lds + 65536 + 16384}};
  char* const sB[2][2] = {{lds + 32768,   lds + 49152},
                          {lds + 65536 + 32768, lds + 65536 + 49152}};

  f32x4 acc[8][4] = {};

  // prologue: tile0 fully; tile1 all but A1 (staged at iter0-ph1)
  stg256(BT, j0, 0,   sB[0][0], t);
  stg256(A,  m0, 0,   sA[0][0], t);
  stg256(BT, j0, 32,  sB[0][1], t);
  stg256(A,  m0, 32,  sA[0][1], t);
  stg256(BT, j0, 64,  sB[1][0], t);
  stg256(A,  m0, 64,  sA[1][0], t);
  stg256(BT, j0, 96,  sB[1][1], t);
  asm volatile("s_waitcnt vmcnt(6)" ::: "memory");
  __builtin_amdgcn_s_barrier();

  #pragma unroll 1
  for (int it = 0; it < 6; ++it){
    const int t1 = 2*it + 1, t2 = 2*it + 2, t3 = 2*it + 3;
    bf16x8 bq[4];
    // ---- tile T0 = 2*it (buf0) ----
    PHASE(0,0,0, { stg256(A, m0, t1*64+32, sA[1][1], t); }, ;);                  // A1(T1)
    PHASE(0,0,1, { if (t2 < 12) stg256(BT, j0, t2*64,    sB[0][0], t); }, ;);    // B0(T2)
    PHASE(0,1,0, { if (t2 < 12) stg256(A,  m0, t2*64,    sA[0][0], t); }, ;);    // A0(T2)
    PHASE(0,1,1, { if (t2 < 12) stg256(BT, j0, t2*64+32, sB[0][1], t); },
                 { if (it == 5) asm volatile("s_waitcnt vmcnt(0)" ::: "memory");
                   else         asm volatile("s_waitcnt vmcnt(6)" ::: "memory"); });
    // ---- tile T1 (buf1) ----
    PHASE(1,0,0, { if (t2 < 12) stg256(A,  m0, t2*64+32, sA[0][1], t); }, ;);    // A1(T2)
    PHASE(1,0,1, { if (t3 < 12) stg256(BT, j0, t3*64,    sB[1][0], t); }, ;);    // B0(T3)
    PHASE(1,1,0, { if (t3 < 12) stg256(A,  m0, t3*64,    sA[1][0], t); }, ;);    // A0(T3)
    PHASE(1,1,1, { if (t3 < 12) stg256(BT, j0, t3*64+32, sB[1][1], t); },
                 { if (it == 5) asm volatile("s_waitcnt vmcnt(0)" ::: "memory");
                   else         asm volatile("s_waitcnt vmcnt(6)" ::: "memory"); });
  }

  const int b = m0 >> 12;
  const int nb = (m0 & 4095) + wm*128 + (lane >> 4)*4;
  #pragma unroll
  for (int mi = 0; mi < 8; mi++){
    #pragma unroll
    for (int ni = 0; ni < 4; ni++){
      const int jc = j0 + wn*64 + ni*16 + (lane & 15);
      const int s  = (jc >= 768);
      const int jl = jc - s * 768;
      const int h  = jl / 48;
      const int c  = jl - h * 48;
      unsigned short* dst = (s ? KT : QT) + (((long)(b*16 + h) * 48 + c) << 12) + nb + mi*16;
      u16x4 pk;
      #pragma unroll
      for (int r = 0; r < 4; r++) pk[r] = f2bf(acc[mi][ni][r]);
      *(u16x4*)dst = pk;
    }
  }
  // per-(row, 128-chunk) sum-of-squares partials (fp32, pre-bf16)
  const int chunk = ((m0 & 4095) >> 7) + wm;   // 32 chunks of 128 per batch-row
  #pragma unroll
  for (int ni = 0; ni < 4; ni++){
    float ss = 0.f;
    #pragma unroll
    for (int mi = 0; mi < 8; mi++)
      #pragma unroll
      for (int r = 0; r < 4; r++) ss += acc[mi][ni][r] * acc[mi][ni][r];
    ss += __shfl_xor(ss, 16);
    ss += __shfl_xor(ss, 32);
    if (lane < 16){
      const int jc = j0 + wn*64 + ni*16 + lane;
      const int s  = (jc >= 768);
      const int jl = jc - s * 768;
      const int h  = jl / 48;
      const int c  = jl - h * 48;
      const int prow = s*6144 + (b*16 + h)*48 + c;
      nrmp[(long)prow*32 + chunk] = ss;
    }
  }
}

// ===== k_gemmP: 128x256 BK=32 ring-3 (r9-proven), x_bf @ WcombT_b -> outF ===
static __device__ __forceinline__ void stageA512(const unsigned short* __restrict__ G, int row0, int ke,
                                                 char* slot, int t){
  const int r  = t >> 2;
  const int k2 = (t & 3) ^ ((r >> 1) & 3);
  GLL((const char*)(G + (long)(row0 + r) * 768 + ke + k2 * 8), slot + (t & 0x1C0) * 16);
}
static __device__ __forceinline__ void stageB512(const unsigned short* __restrict__ G, int row0, int ke,
                                                 char* slot, int t){
  #pragma unroll
  for (int l = 0; l < 2; l++){
    const int r  = l*128 + (t >> 2);
    const int k2 = (t & 3) ^ ((r >> 1) & 3);
    GLL((const char*)(G + (long)(row0 + r) * 768 + ke + k2 * 8), slot + l*8192 + (t & 0x1C0) * 16);
  }
}

#define VM0 asm volatile("s_waitcnt vmcnt(0)" ::: "memory")
#define VM3 asm volatile("s_waitcnt vmcnt(3)" ::: "memory")

#define PHASE1(CUR, STAGE_STMT, WAIT_STMT) do {                                \
    bf16x8 af[4], bq[4];                                                       \
    _Pragma("unroll")                                                          \
    for (int ni = 0; ni < 4; ni++)                                             \
      bq[ni] = ldfrag(sB[CUR], wn*64 + ni*16 + arow, ko);                      \
    _Pragma("unroll")                                                          \
    for (int mi = 0; mi < 4; mi++)                                             \
      af[mi] = ldfrag(sA[CUR], wm64 + mi*16 + arow, ko);                       \
    __builtin_amdgcn_s_barrier();                                              \
    __builtin_amdgcn_s_setprio(1);                                             \
    _Pragma("unroll")                                                          \
    for (int mi = 0; mi < 4; mi++)                                             \
      _Pragma("unroll")                                                        \
      for (int ni = 0; ni < 4; ni++)                                           \
        acc[mi][ni] = __builtin_amdgcn_mfma_f32_16x16x32_bf16(                 \
            af[mi], bq[ni], acc[mi][ni], 0, 0, 0);                             \
    __builtin_amdgcn_s_setprio(0);                                             \
    STAGE_STMT;                                                                \
    WAIT_STMT;                                                                 \
    __builtin_amdgcn_s_barrier();                                              \
  } while(0)

__global__ __launch_bounds__(512, 4)
void k_gemmP(const unsigned short* __restrict__ A, const unsigned short* __restrict__ BT,
             float* __restrict__ OUTF, const float* __restrict__ bias)
{
  __shared__ __attribute__((aligned(16))) char lds[73728];
  const int o  = blockIdx.x;
  const int wg = (o & 7) * 96 + (o >> 3);                  // 768 wgs
  const int jt = wg % 3, mt = wg / 3;
  const int m0 = mt * 128, j0 = jt * 256;
  const int t = threadIdx.x, lane = t & 63, w = t >> 6;
  const int wm = w >> 2, wn = w & 3;
  const int wm64 = wm * 64;
  const int arow = lane & 15, ko = lane >> 4;
  const unsigned short* BTb = BT + ((long)(m0 >> 12)) * 589824;

  char* const sA[3] = {lds,          lds + 8192,          lds + 16384};
  char* const sB[3] = {lds + 24576,  lds + 24576 + 16384, lds + 24576 + 32768};

  f32x4 acc[4][4] = {};

  stageA512(A, m0, 0,  sA[0], t);  stageB512(BTb, j0, 0,  sB[0], t);
  stageA512(A, m0, 32, sA[1], t);  stageB512(BTb, j0, 32, sB[1], t);
  VM3;
  __builtin_amdgcn_s_barrier();

  #pragma unroll 1
  for (int g = 0; g < 7; ++g){
    const int kb = g * 96;
    PHASE1(0, { stageA512(A, m0, kb+64,  sA[2], t); stageB512(BTb, j0, kb+64,  sB[2], t); }, VM3);
    PHASE1(1, { stageA512(A, m0, kb+96,  sA[0], t); stageB512(BTb, j0, kb+96,  sB[0], t); }, VM3);
    PHASE1(2, { stageA512(A, m0, kb+128, sA[1], t); stageB512(BTb, j0, kb+128, sB[1], t); }, VM3);
  }
  PHASE1(0, { stageA512(A, m0, 736, sA[2], t); stageB512(BTb, j0, 736, sB[2], t); }, VM3);
  PHASE1(1, { ; }, VM0);
  PHASE1(2, { ; }, ;);

  #pragma unroll
  for (int mi = 0; mi < 4; mi++){
    #pragma unroll
    for (int ni = 0; ni < 4; ni++){
      const int jc = j0 + wn*64 + ni*16 + (lane & 15);
      const float bv = bias[jc];
      const long mr = (long)m0 + wm64 + mi*16 + (lane >> 4)*4;
      #pragma unroll
      for (int r = 0; r < 4; r++) OUTF[(mr + r) * 768 + jc] = acc[mi][ni][r] + bv;
    }
  }
}

// ---------------- S partials: per (bh, ksp) 48x48 over 1024 n ---------------
__global__ __launch_bounds__(256)
void k_attn_part(const unsigned short* __restrict__ QT, const unsigned short* __restrict__ KT,
                 float* __restrict__ Spart)
{
  __shared__ float Sl[4][2304];
  const int bh = blockIdx.x, ksp = blockIdx.y;
  const int t = threadIdx.x, lane = t & 63, w = t >> 6;
  const unsigned short* qb = QT + ((long)bh * 48 << 12);
  const unsigned short* kb = KT + ((long)bh * 48 << 12);
  const int n00 = ksp * 1024 + w * 256;
  f32x4 acc[3][3] = {};
  for (int kt = 0; kt < 256; kt += 32){
    bf16x8 af[3], bfr[3];
    #pragma unroll
    for (int ci = 0; ci < 3; ci++)
      af[ci]  = *(const bf16x8*)(qb + ((long)(ci*16 + (lane & 15)) << 12) + n00 + kt + (lane >> 4) * 8);
    #pragma unroll
    for (int di = 0; di < 3; di++)
      bfr[di] = *(const bf16x8*)(kb + ((long)(di*16 + (lane & 15)) << 12) + n00 + kt + (lane >> 4) * 8);
    #pragma unroll
    for (int ci = 0; ci < 3; ci++)
      #pragma unroll
      for (int di = 0; di < 3; di++)
        acc[ci][di] = __builtin_amdgcn_mfma_f32_16x16x32_bf16(af[ci], bfr[di], acc[ci][di], 0, 0, 0);
  }
  #pragma unroll
  for (int ci = 0; ci < 3; ci++)
    #pragma unroll
    for (int di = 0; di < 3; di++)
      #pragma unroll
      for (int r = 0; r < 4; r++)
        Sl[w][(ci*16 + (lane >> 4)*4 + r) * 48 + di*16 + (lane & 15)] = acc[ci][di][r];
  __syncthreads();
  float* outp = Spart + ((long)ksp * 128 + bh) * 2304;
  for (int idx = t; idx < 2304; idx += 256)
    outp[idx] = Sl[0][idx] + Sl[1][idx] + Sl[2][idx] + Sl[3][idx];
}

// --- reduce partials + norms, scale, softmax -> attnT bf16 [bh][48 d][64 c] --
__global__ void k_softmax(const float* __restrict__ Spart, const float* __restrict__ nrmp,
                          const float* __restrict__ temp, unsigned short* __restrict__ attnT)
{
  __shared__ float invq[48], invk[48];
  const int bh = blockIdx.x, h = bh & 15;
  const int c = threadIdx.x;   // 64 threads, 48 active
  if (c < 48){
    float sq = 0.f, sk = 0.f;
    const float* pq = nrmp + (long)(bh*48 + c) * 32;
    const float* pk = nrmp + (long)(6144 + bh*48 + c) * 32;
    #pragma unroll
    for (int i = 0; i < 32; i++){ sq += pq[i]; sk += pk[i]; }
    invq[c] = 1.0f / fmaxf(sqrtf(sq), 1e-12f);
    invk[c] = 1.0f / fmaxf(sqrtf(sk), 1e-12f);
  }
  __syncthreads();
  if (c < 48){
    const float scq = invq[c] * temp[h];
    float row[48];
    #pragma unroll
    for (int d = 0; d < 48; d++){
      long base = ((long)bh * 48 + c) * 48 + d;
      float v = Spart[base] + Spart[base + 128L*2304] + Spart[base + 256L*2304] + Spart[base + 384L*2304];
      row[d] = v * scq * invk[d];
    }
    float mx = -1e30f;
    #pragma unroll
    for (int d = 0; d < 48; d++) mx = fmaxf(mx, row[d]);
    float s = 0.f;
    #pragma unroll
    for (int d = 0; d < 48; d++){ row[d] = expf(row[d] - mx); s += row[d]; }
    const float inv = 1.0f / s;
    unsigned short* ob = attnT + (long)bh * 48 * 64;
    #pragma unroll
    for (int d = 0; d < 48; d++) ob[d*64 + c] = f2bf(row[d] * inv);
    u16x8 z = {};
    *(u16x8*)(ob + c*64 + 48) = z;
    *(u16x8*)(ob + c*64 + 56) = z;
  }
}

// --- WmodT[b][j][h*48+d] = sum_c attnT[bh][d][c] * WpT[j][h*48+c] (MFMA) -----
__global__ __launch_bounds__(256)
void k_wmod2(const unsigned short* __restrict__ WpT, const unsigned short* __restrict__ attnT,
             unsigned short* __restrict__ WmodT)
{
  const int j0 = blockIdx.x * 256, h = blockIdx.y, b = blockIdx.z;
  const int t = threadIdx.x, lane = t & 63, w = t >> 6;
  const unsigned short* wp = WpT + h * 48;
  const unsigned short* ab = attnT + ((long)(b*16 + h)) * 48 * 64;
  f32x4 acc[4][3] = {};
  #pragma unroll
  for (int kt = 0; kt < 64; kt += 32){
    bf16x8 bfr[3];
    #pragma unroll
    for (int ni = 0; ni < 3; ni++)
      bfr[ni] = *(const bf16x8*)(ab + (ni*16 + (lane & 15))*64 + kt + (lane >> 4)*8);
    #pragma unroll
    for (int mi = 0; mi < 4; mi++){
      const int j = j0 + w*64 + mi*16 + (lane & 15);
      bf16x8 a = *(const bf16x8*)(wp + (long)j*768 + kt + (lane >> 4)*8);
      #pragma unroll
      for (int ni = 0; ni < 3; ni++)
        acc[mi][ni] = __builtin_amdgcn_mfma_f32_16x16x32_bf16(a, bfr[ni], acc[mi][ni], 0, 0, 0);
    }
  }
  #pragma unroll
  for (int mi = 0; mi < 4; mi++)
    #pragma unroll
    for (int ni = 0; ni < 3; ni++)
      #pragma unroll
      for (int r = 0; r < 4; r++){
        const int j = j0 + w*64 + mi*16 + (lane >> 4)*4 + r;
        const int d = ni*16 + (lane & 15);
        WmodT[(long)b*589824 + (long)j*768 + h*48 + d] = f2bf(acc[mi][ni][r]);
      }
}

// --- WcombT[6144 rows=b*768+j][768 e] = WmodT[row][hd] @ WvB[e][hd] (128² tile)
__global__ __launch_bounds__(256)
void k_comb(const unsigned short* __restrict__ A, const unsigned short* __restrict__ BT,
            unsigned short* __restrict__ OUT)
{
  __shared__ unsigned short As[128 * 32];
  __shared__ unsigned short Bs[128 * 32];
  const int m0 = blockIdx.y * 128;
  const int j0 = blockIdx.x * 128;
  const int t = threadIdx.x;
  const int lane = t & 63;
  const int w = t >> 6, wm = w >> 1, wn = w & 1;

  f32x4 acc[4][4] = {};

  for (int kt = 0; kt < 768; kt += 32){
    if (kt) __syncthreads();
    #pragma unroll
    for (int i = 0; i < 2; i++){
      const char* ga = (const char*)A  + (long)(m0 + i*64 + (t >> 2)) * 1536 + kt*2 + (t & 3) * 16;
      const char* gb = (const char*)BT + (long)(j0 + i*64 + (t >> 2)) * 1536 + kt*2 + (t & 3) * 16;
      char* la = (char*)As + i*4096 + (t & 0xC0) * 16;
      char* lb = (char*)Bs + i*4096 + (t & 0xC0) * 16;
      GLL(ga, la);
      GLL(gb, lb);
    }
    __syncthreads();
    bf16x8 af[4], bfr[4];
    #pragma unroll
    for (int mi = 0; mi < 4; mi++)
      af[mi]  = *(const bf16x8*)&As[(wm*64 + mi*16 + (lane & 15)) * 32 + (lane >> 4) * 8];
    #pragma unroll
    for (int ni = 0; ni < 4; ni++)
      bfr[ni] = *(const bf16x8*)&Bs[(wn*64 + ni*16 + (lane & 15)) * 32 + (lane >> 4) * 8];
    #pragma unroll
    for (int mi = 0; mi < 4; mi++)
      #pragma unroll
      for (int ni = 0; ni < 4; ni++)
        acc[mi][ni] = __builtin_amdgcn_mfma_f32_16x16x32_bf16(af[mi], bfr[ni], acc[mi][ni], 0, 0, 0);
  }

  #pragma unroll
  for (int mi = 0; mi < 4; mi++)
    #pragma unroll
    for (int ni = 0; ni < 4; ni++){
      const int jc = j0 + wn*64 + ni*16 + (lane & 15);
      const long mr = (long)m0 + wm*64 + mi*16 + (lane >> 4) * 4;
      #pragma unroll
      for (int r = 0; r < 4; r++) OUT[(mr + r) * 768 + jc] = f2bf(acc[mi][ni][r]);
    }
}

extern "C" void kernel_launch(void* const* d_in, const int* in_sizes, int n_in,
                              void* d_out, int out_size, void* d_ws, size_t ws_size,
                              hipStream_t stream)
{
  (void)in_sizes; (void)n_in; (void)out_size; (void)ws_size;
  const float* x      = (const float*)d_in[0];
  const float* w_qkv  = (const float*)d_in[1];
  const float* temp   = (const float*)d_in[2];
  const float* w_proj = (const float*)d_in[3];
  const float* b_proj = (const float*)d_in[4];
  float* outF = (float*)d_out;

  char* ws = (char*)d_ws;
  size_t off = 0;
  auto alloc = [&](size_t bytes)->char*{ char* p = ws + off; off += (bytes + 255) & ~(size_t)255; return p; };

  unsigned short* x_bf  = (unsigned short*)alloc(50331648);           // [32768][768] bf16
  unsigned short* WT    = (unsigned short*)alloc(2359296);            // [1536 q||k][768] bf16
  unsigned short* WpT   = (unsigned short*)alloc(1179648);            // [768][768] bf16
  unsigned short* WvB   = (unsigned short*)alloc(1179648);            // [768 e][768 hd] bf16
  unsigned short* QT    = (unsigned short*)alloc(100663296);          // QT||KT [6144][4096] bf16 each
  unsigned short* KT    = QT + (long)6144 * 4096;
  float* nrmp           = (float*)alloc(12288L * 32 * 4);             // [12288 rows][32 chunks] f32
  float* Spart          = (float*)alloc(4L * 128 * 2304 * 4);         // [4][128][48][48] f32
  unsigned short* attnT = (unsigned short*)alloc(786432);             // [128][48 d][64 c] bf16
  unsigned short* WmodT = (unsigned short*)alloc(9437184);            // [8][768 j][768 hd] bf16
  unsigned short* WcombT= (unsigned short*)alloc(9437184);            // [8][768 j][768 e] bf16

  k_cvt<<<12288, 256, 0, stream>>>(x, x_bf, 25165824L);
  k_tconv<<<dim3(24, 12), 256, 0, stream>>>(w_qkv, WT, 768, 2304);    // q||k cols only
  k_tconv<<<dim3(12, 12), 256, 0, stream>>>(w_proj, WpT, 768, 768);
  k_cvtwv<<<288, 256, 0, stream>>>(w_qkv, WvB);
  k_gemm256<<<768, 512, 0, stream>>>(x_bf, WT, QT, KT, nrmp);
  k_attn_part<<<dim3(128, 4), 256, 0, stream>>>(QT, KT, Spart);
  k_softmax<<<128, 64, 0, stream>>>(Spart, nrmp, temp, attnT);
  k_wmod2<<<dim3(3, 16, 8), 256, 0, stream>>>(WpT, attnT, WmodT);
  k_comb<<<dim3(6, 48), 256, 0, stream>>>(WmodT, WvB, WcombT);
  k_gemmP<<<768, 512, 0, stream>>>(x_bf, WcombT, outF, b_proj);
}

// Round 12
// 240.446 us; speedup vs baseline: 1.1874x; 1.0035x over previous
//
#include <hip/hip_runtime.h>
#include <stdint.h>

typedef __attribute__((ext_vector_type(4))) float          f32x4;
typedef __attribute__((ext_vector_type(8))) short          bf16x8;
typedef __attribute__((ext_vector_type(8))) unsigned short u16x8;
typedef __attribute__((ext_vector_type(4))) unsigned short u16x4;

static __device__ __forceinline__ unsigned short f2bf(float f){
  uint32_t u = __builtin_bit_cast(uint32_t, f);
  u += 0x7FFFu + ((u >> 16) & 1u);          // RNE
  return (unsigned short)(u >> 16);
}
static __device__ __forceinline__ float bf2f(unsigned short h){
  uint32_t u = ((uint32_t)h) << 16;
  return __builtin_bit_cast(float, u);
}

#define GLL(SRC, DST) __builtin_amdgcn_global_load_lds(                         \
    (const __attribute__((address_space(1))) unsigned int*)(SRC),               \
    (__attribute__((address_space(3))) unsigned int*)(DST), 16, 0, 0)

// ---------------- elementwise convert f32 -> bf16 (8/thread) ----------------
__global__ void k_cvt(const float* __restrict__ in, unsigned short* __restrict__ out, long n){
  long i = ((long)blockIdx.x * blockDim.x + threadIdx.x) * 8;
  if (i >= n) return;
  const f32x4* p = (const f32x4*)(in + i);
  f32x4 a = p[0], b = p[1];
  u16x8 o;
  #pragma unroll
  for (int j = 0; j < 4; j++){ o[j] = f2bf(a[j]); o[4+j] = f2bf(b[j]); }
  *(u16x8*)(out + i) = o;
}

// ---------------- tiled transpose+convert: in[R][C] f32 -> out[C][R] bf16 ----
__global__ void k_tconv(const float* __restrict__ in, unsigned short* __restrict__ out, int R, int C){
  __shared__ float tl[64][65];
  const int c0 = blockIdx.x * 64, r0 = blockIdx.y * 64;
  const int t = threadIdx.x;
  {
    const int lr = t >> 2, lc = (t & 3) * 16;
    const f32x4* s = (const f32x4*)(in + (long)(r0 + lr) * C + c0 + lc);
    #pragma unroll
    for (int q = 0; q < 4; q++){
      f32x4 v = s[q];
      #pragma unroll
      for (int j = 0; j < 4; j++) tl[lr][lc + q*4 + j] = v[j];
    }
  }
  __syncthreads();
  {
    const int oc = t >> 2, orr = (t & 3) * 16;
    u16x8 o0, o1;
    #pragma unroll
    for (int i = 0; i < 8; i++){ o0[i] = f2bf(tl[orr + i][oc]); o1[i] = f2bf(tl[orr + 8 + i][oc]); }
    u16x8* dst = (u16x8*)(out + (long)(c0 + oc) * R + r0 + orr);
    dst[0] = o0; dst[1] = o1;
  }
}

// ------- strided cvt: WvB[e][hd] = bf16(w_qkv[e][1536+hd]), 768x768 ---------
__global__ void k_cvtwv(const float* __restrict__ w, unsigned short* __restrict__ out){
  const long idx = ((long)blockIdx.x * blockDim.x + threadIdx.x) * 8;
  const int e = (int)(idx / 768), hd = (int)(idx - (long)e * 768);
  const float* s = w + (long)e * 2304 + 1536 + hd;
  f32x4 a = *(const f32x4*)s, b = *(const f32x4*)(s + 4);
  u16x8 o;
  #pragma unroll
  for (int j = 0; j < 4; j++){ o[j] = f2bf(a[j]); o[4+j] = f2bf(b[j]); }
  *(u16x8*)(out + idx) = o;
}

// ===================== shared fragment read (conflict-free swizzle) =========
// 64B K32 rows; LDS chunk c of row r holds global k-chunk (c ^ ((r>>1)&3)).
// Verified 0 bank conflicts (r10/r11).
static __device__ __forceinline__ bf16x8 ldfrag(const char* slot, int row, int ko){
  const int k2 = (ko ^ (row >> 1)) & 3;
  return *(const bf16x8*)(slot + row*64 + k2*16);
}

// ========== k_gemm256: 256x256 8-phase, T2 swizzle + m201-faithful order ====
// Phase: reads; STAGE-EARLY; sched_barrier; barrier; lgkm(0); sched_barrier;
// setprio; 16 MFMA; setprio; [vmcnt(6) at ph4/8]; barrier.
// Stage-early WAR safe: slot last-read at phase p-1 drains at its lgkm(0)
// before barrier2(p-1) < phase-p stage issue.
static __device__ __forceinline__ void stg256(const unsigned short* __restrict__ G, int row0, int ke,
                                              char* lds_slot, int t){
  #pragma unroll
  for (int l = 0; l < 2; l++){
    const int r  = l*128 + (t >> 2);
    const int k2 = (t & 3) ^ ((r >> 1) & 3);
    GLL((const char*)(G + (long)(row0 + r) * 768 + ke + k2 * 8),
        lds_slot + l*8192 + (t & 0x1C0) * 16);
  }
}

#define PHASE(BUF, KK, MH, STAGE_STMT, WAIT_STMT) do {                         \
    bf16x8 af[4];                                                              \
    if (MH == 0) {                                                             \
      _Pragma("unroll")                                                        \
      for (int ni = 0; ni < 4; ni++)                                           \
        bq[ni] = ldfrag(sB[BUF][KK], wn*64 + ni*16 + arow, ko);                \
    }                                                                          \
    _Pragma("unroll")                                                          \
    for (int mi = 0; mi < 4; mi++)                                             \
      af[mi] = ldfrag(sA[BUF][KK], wm*128 + MH*64 + mi*16 + arow, ko);         \
    STAGE_STMT;                                                                \
    __builtin_amdgcn_sched_barrier(0);                                         \
    __builtin_amdgcn_s_barrier();                                              \
    asm volatile("s_waitcnt lgkmcnt(0)" ::: "memory");                         \
    __builtin_amdgcn_sched_barrier(0);                                         \
    __builtin_amdgcn_s_setprio(1);                                             \
    _Pragma("unroll")                                                          \
    for (int mi = 0; mi < 4; mi++)                                             \
      _Pragma("unroll")                                                        \
      for (int ni = 0; ni < 4; ni++)                                           \
        acc[MH*4+mi][ni] = __builtin_amdgcn_mfma_f32_16x16x32_bf16(            \
            af[mi], bq[ni], acc[MH*4+mi][ni], 0, 0, 0);                        \
    __builtin_amdgcn_s_setprio(0);                                             \
    __builtin_amdgcn_sched_barrier(0);                                         \
    WAIT_STMT;                                                                 \
    __builtin_amdgcn_s_barrier();                                              \
  } while(0)

// A=x_bf[32768][768], BT=WT[1536 q||k][768] -> QT/KT (transposed) + nrmp
__global__ __launch_bounds__(512, 2)
void k_gemm256(const unsigned short* __restrict__ A, const unsigned short* __restrict__ BT,
               unsigned short* __restrict__ QT, unsigned short* __restrict__ KT,
               float* __restrict__ nrmp)
{
  __shared__ __attribute__((aligned(16))) char lds[131072];
  const int o  = blockIdx.x;
  const int wg = (o & 7) * 96 + (o >> 3);          // bijective XCD swizzle, 768 wgs
  const int jt = wg % 6, mt = wg / 6;
  const int m0 = mt * 256, j0 = jt * 256;
  const int t = threadIdx.x, lane = t & 63, w = t >> 6;
  const int wm = w >> 2, wn = w & 3;
  const int arow = lane & 15, ko = lane >> 4;

  char* const sA[2][2] = {{lds,           lds + 16384},
                          {lds + 65536,   lds + 65536 + 16384}};
  char* const sB[2][2] = {{lds + 32768,   lds + 49152},
                          {lds + 65536 + 32768, lds + 65536 + 49152}};

  f32x4 acc[8][4] = {};

  // prologue: tile0 fully; tile1 all but A1 (staged at iter0-ph1)
  stg256(BT, j0, 0,   sB[0][0], t);
  stg256(A,  m0, 0,   sA[0][0], t);
  stg256(BT, j0, 32,  sB[0][1], t);
  stg256(A,  m0, 32,  sA[0][1], t);
  stg256(BT, j0, 64,  sB[1][0], t);
  stg256(A,  m0, 64,  sA[1][0], t);
  stg256(BT, j0, 96,  sB[1][1], t);
  asm volatile("s_waitcnt vmcnt(6)" ::: "memory");
  __builtin_amdgcn_s_barrier();

  #pragma unroll 1
  for (int it = 0; it < 6; ++it){
    const int t1 = 2*it + 1, t2 = 2*it + 2, t3 = 2*it + 3;
    bf16x8 bq[4];
    // ---- tile T0 = 2*it (buf0) ----
    PHASE(0,0,0, { stg256(A, m0, t1*64+32, sA[1][1], t); }, ;);                  // A1(T1)
    PHASE(0,0,1, { if (t2 < 12) stg256(BT, j0, t2*64,    sB[0][0], t); }, ;);    // B0(T2)
    PHASE(0,1,0, { if (t2 < 12) stg256(A,  m0, t2*64,    sA[0][0], t); }, ;);    // A0(T2)
    PHASE(0,1,1, { if (t2 < 12) stg256(BT, j0, t2*64+32, sB[0][1], t); },
                 { if (it == 5) asm volatile("s_waitcnt vmcnt(0)" ::: "memory");
                   else         asm volatile("s_waitcnt vmcnt(6)" ::: "memory"); });
    // ---- tile T1 (buf1) ----
    PHASE(1,0,0, { if (t2 < 12) stg256(A,  m0, t2*64+32, sA[0][1], t); }, ;);    // A1(T2)
    PHASE(1,0,1, { if (t3 < 12) stg256(BT, j0, t3*64,    sB[1][0], t); }, ;);    // B0(T3)
    PHASE(1,1,0, { if (t3 < 12) stg256(A,  m0, t3*64,    sA[1][0], t); }, ;);    // A0(T3)
    PHASE(1,1,1, { if (t3 < 12) stg256(BT, j0, t3*64+32, sB[1][1], t); },
                 { if (it == 5) asm volatile("s_waitcnt vmcnt(0)" ::: "memory");
                   else         asm volatile("s_waitcnt vmcnt(6)" ::: "memory"); });
  }

  const int b = m0 >> 12;
  const int nb = (m0 & 4095) + wm*128 + (lane >> 4)*4;
  #pragma unroll
  for (int mi = 0; mi < 8; mi++){
    #pragma unroll
    for (int ni = 0; ni < 4; ni++){
      const int jc = j0 + wn*64 + ni*16 + (lane & 15);
      const int s  = (jc >= 768);
      const int jl = jc - s * 768;
      const int h  = jl / 48;
      const int c  = jl - h * 48;
      unsigned short* dst = (s ? KT : QT) + (((long)(b*16 + h) * 48 + c) << 12) + nb + mi*16;
      u16x4 pk;
      #pragma unroll
      for (int r = 0; r < 4; r++) pk[r] = f2bf(acc[mi][ni][r]);
      *(u16x4*)dst = pk;
    }
  }
  // per-(row, 128-chunk) sum-of-squares partials (fp32, pre-bf16)
  const int chunk = ((m0 & 4095) >> 7) + wm;   // 32 chunks of 128 per batch-row
  #pragma unroll
  for (int ni = 0; ni < 4; ni++){
    float ss = 0.f;
    #pragma unroll
    for (int mi = 0; mi < 8; mi++)
      #pragma unroll
      for (int r = 0; r < 4; r++) ss += acc[mi][ni][r] * acc[mi][ni][r];
    ss += __shfl_xor(ss, 16);
    ss += __shfl_xor(ss, 32);
    if (lane < 16){
      const int jc = j0 + wn*64 + ni*16 + lane;
      const int s  = (jc >= 768);
      const int jl = jc - s * 768;
      const int h  = jl / 48;
      const int c  = jl - h * 48;
      const int prow = s*6144 + (b*16 + h)*48 + c;
      nrmp[(long)prow*32 + chunk] = ss;
    }
  }
}

// ===== k_gemmP: 128x256 BK=32 ring-3 (r9-proven), x_bf @ WcombT_b -> outF ===
static __device__ __forceinline__ void stageA512(const unsigned short* __restrict__ G, int row0, int ke,
                                                 char* slot, int t){
  const int r  = t >> 2;
  const int k2 = (t & 3) ^ ((r >> 1) & 3);
  GLL((const char*)(G + (long)(row0 + r) * 768 + ke + k2 * 8), slot + (t & 0x1C0) * 16);
}
static __device__ __forceinline__ void stageB512(const unsigned short* __restrict__ G, int row0, int ke,
                                                 char* slot, int t){
  #pragma unroll
  for (int l = 0; l < 2; l++){
    const int r  = l*128 + (t >> 2);
    const int k2 = (t & 3) ^ ((r >> 1) & 3);
    GLL((const char*)(G + (long)(row0 + r) * 768 + ke + k2 * 8), slot + l*8192 + (t & 0x1C0) * 16);
  }
}

#define VM0 asm volatile("s_waitcnt vmcnt(0)" ::: "memory")
#define VM3 asm volatile("s_waitcnt vmcnt(3)" ::: "memory")

#define PHASE1(CUR, STAGE_STMT, WAIT_STMT) do {                                \
    bf16x8 af[4], bq[4];                                                       \
    _Pragma("unroll")                                                          \
    for (int ni = 0; ni < 4; ni++)                                             \
      bq[ni] = ldfrag(sB[CUR], wn*64 + ni*16 + arow, ko);                      \
    _Pragma("unroll")                                                          \
    for (int mi = 0; mi < 4; mi++)                                             \
      af[mi] = ldfrag(sA[CUR], wm64 + mi*16 + arow, ko);                       \
    __builtin_amdgcn_s_barrier();                                              \
    __builtin_amdgcn_s_setprio(1);                                             \
    _Pragma("unroll")                                                          \
    for (int mi = 0; mi < 4; mi++)                                             \
      _Pragma("unroll")                                                        \
      for (int ni = 0; ni < 4; ni++)                                           \
        acc[mi][ni] = __builtin_amdgcn_mfma_f32_16x16x32_bf16(                 \
            af[mi], bq[ni], acc[mi][ni], 0, 0, 0);                             \
    __builtin_amdgcn_s_setprio(0);                                             \
    STAGE_STMT;                                                                \
    WAIT_STMT;                                                                 \
    __builtin_amdgcn_s_barrier();                                              \
  } while(0)

__global__ __launch_bounds__(512, 4)
void k_gemmP(const unsigned short* __restrict__ A, const unsigned short* __restrict__ BT,
             float* __restrict__ OUTF, const float* __restrict__ bias)
{
  __shared__ __attribute__((aligned(16))) char lds[73728];
  const int o  = blockIdx.x;
  const int wg = (o & 7) * 96 + (o >> 3);                  // 768 wgs
  const int jt = wg % 3, mt = wg / 3;
  const int m0 = mt * 128, j0 = jt * 256;
  const int t = threadIdx.x, lane = t & 63, w = t >> 6;
  const int wm = w >> 2, wn = w & 3;
  const int wm64 = wm * 64;
  const int arow = lane & 15, ko = lane >> 4;
  const unsigned short* BTb = BT + ((long)(m0 >> 12)) * 589824;

  char* const sA[3] = {lds,          lds + 8192,          lds + 16384};
  char* const sB[3] = {lds + 24576,  lds + 24576 + 16384, lds + 24576 + 32768};

  f32x4 acc[4][4] = {};

  stageA512(A, m0, 0,  sA[0], t);  stageB512(BTb, j0, 0,  sB[0], t);
  stageA512(A, m0, 32, sA[1], t);  stageB512(BTb, j0, 32, sB[1], t);
  VM3;
  __builtin_amdgcn_s_barrier();

  #pragma unroll 1
  for (int g = 0; g < 7; ++g){
    const int kb = g * 96;
    PHASE1(0, { stageA512(A, m0, kb+64,  sA[2], t); stageB512(BTb, j0, kb+64,  sB[2], t); }, VM3);
    PHASE1(1, { stageA512(A, m0, kb+96,  sA[0], t); stageB512(BTb, j0, kb+96,  sB[0], t); }, VM3);
    PHASE1(2, { stageA512(A, m0, kb+128, sA[1], t); stageB512(BTb, j0, kb+128, sB[1], t); }, VM3);
  }
  PHASE1(0, { stageA512(A, m0, 736, sA[2], t); stageB512(BTb, j0, 736, sB[2], t); }, VM3);
  PHASE1(1, { ; }, VM0);
  PHASE1(2, { ; }, ;);

  #pragma unroll
  for (int mi = 0; mi < 4; mi++){
    #pragma unroll
    for (int ni = 0; ni < 4; ni++){
      const int jc = j0 + wn*64 + ni*16 + (lane & 15);
      const float bv = bias[jc];
      const long mr = (long)m0 + wm64 + mi*16 + (lane >> 4)*4;
      #pragma unroll
      for (int r = 0; r < 4; r++) OUTF[(mr + r) * 768 + jc] = acc[mi][ni][r] + bv;
    }
  }
}

// ---------------- S partials: per (bh, ksp) 48x48 over 1024 n ---------------
__global__ __launch_bounds__(256)
void k_attn_part(const unsigned short* __restrict__ QT, const unsigned short* __restrict__ KT,
                 float* __restrict__ Spart)
{
  __shared__ float Sl[4][2304];
  const int bh = blockIdx.x, ksp = blockIdx.y;
  const int t = threadIdx.x, lane = t & 63, w = t >> 6;
  const unsigned short* qb = QT + ((long)bh * 48 << 12);
  const unsigned short* kb = KT + ((long)bh * 48 << 12);
  const int n00 = ksp * 1024 + w * 256;
  f32x4 acc[3][3] = {};
  for (int kt = 0; kt < 256; kt += 32){
    bf16x8 af[3], bfr[3];
    #pragma unroll
    for (int ci = 0; ci < 3; ci++)
      af[ci]  = *(const bf16x8*)(qb + ((long)(ci*16 + (lane & 15)) << 12) + n00 + kt + (lane >> 4) * 8);
    #pragma unroll
    for (int di = 0; di < 3; di++)
      bfr[di] = *(const bf16x8*)(kb + ((long)(di*16 + (lane & 15)) << 12) + n00 + kt + (lane >> 4) * 8);
    #pragma unroll
    for (int ci = 0; ci < 3; ci++)
      #pragma unroll
      for (int di = 0; di < 3; di++)
        acc[ci][di] = __builtin_amdgcn_mfma_f32_16x16x32_bf16(af[ci], bfr[di], acc[ci][di], 0, 0, 0);
  }
  #pragma unroll
  for (int ci = 0; ci < 3; ci++)
    #pragma unroll
    for (int di = 0; di < 3; di++)
      #pragma unroll
      for (int r = 0; r < 4; r++)
        Sl[w][(ci*16 + (lane >> 4)*4 + r) * 48 + di*16 + (lane & 15)] = acc[ci][di][r];
  __syncthreads();
  float* outp = Spart + ((long)ksp * 128 + bh) * 2304;
  for (int idx = t; idx < 2304; idx += 256)
    outp[idx] = Sl[0][idx] + Sl[1][idx] + Sl[2][idx] + Sl[3][idx];
}

// --- reduce partials + norms, scale, softmax -> attnT bf16 [bh][48 d][64 c] --
__global__ void k_softmax(const float* __restrict__ Spart, const float* __restrict__ nrmp,
                          const float* __restrict__ temp, unsigned short* __restrict__ attnT)
{
  __shared__ float invq[48], invk[48];
  const int bh = blockIdx.x, h = bh & 15;
  const int c = threadIdx.x;   // 64 threads, 48 active
  if (c < 48){
    float sq = 0.f, sk = 0.f;
    const float* pq = nrmp + (long)(bh*48 + c) * 32;
    const float* pk = nrmp + (long)(6144 + bh*48 + c) * 32;
    #pragma unroll
    for (int i = 0; i < 32; i++){ sq += pq[i]; sk += pk[i]; }
    invq[c] = 1.0f / fmaxf(sqrtf(sq), 1e-12f);
    invk[c] = 1.0f / fmaxf(sqrtf(sk), 1e-12f);
  }
  __syncthreads();
  if (c < 48){
    const float scq = invq[c] * temp[h];
    float row[48];
    #pragma unroll
    for (int d = 0; d < 48; d++){
      long base = ((long)bh * 48 + c) * 48 + d;
      float v = Spart[base] + Spart[base + 128L*2304] + Spart[base + 256L*2304] + Spart[base + 384L*2304];
      row[d] = v * scq * invk[d];
    }
    float mx = -1e30f;
    #pragma unroll
    for (int d = 0; d < 48; d++) mx = fmaxf(mx, row[d]);
    float s = 0.f;
    #pragma unroll
    for (int d = 0; d < 48; d++){ row[d] = expf(row[d] - mx); s += row[d]; }
    const float inv = 1.0f / s;
    unsigned short* ob = attnT + (long)bh * 48 * 64;
    #pragma unroll
    for (int d = 0; d < 48; d++) ob[d*64 + c] = f2bf(row[d] * inv);
    u16x8 z = {};
    *(u16x8*)(ob + c*64 + 48) = z;
    *(u16x8*)(ob + c*64 + 56) = z;
  }
}

// --- WmodT[b][j][h*48+d] = sum_c attnT[bh][d][c] * WpT[j][h*48+c] (MFMA) -----
__global__ __launch_bounds__(256)
void k_wmod2(const unsigned short* __restrict__ WpT, const unsigned short* __restrict__ attnT,
             unsigned short* __restrict__ WmodT)
{
  const int j0 = blockIdx.x * 256, h = blockIdx.y, b = blockIdx.z;
  const int t = threadIdx.x, lane = t & 63, w = t >> 6;
  const unsigned short* wp = WpT + h * 48;
  const unsigned short* ab = attnT + ((long)(b*16 + h)) * 48 * 64;
  f32x4 acc[4][3] = {};
  #pragma unroll
  for (int kt = 0; kt < 64; kt += 32){
    bf16x8 bfr[3];
    #pragma unroll
    for (int ni = 0; ni < 3; ni++)
      bfr[ni] = *(const bf16x8*)(ab + (ni*16 + (lane & 15))*64 + kt + (lane >> 4)*8);
    #pragma unroll
    for (int mi = 0; mi < 4; mi++){
      const int j = j0 + w*64 + mi*16 + (lane & 15);
      bf16x8 a = *(const bf16x8*)(wp + (long)j*768 + kt + (lane >> 4)*8);
      #pragma unroll
      for (int ni = 0; ni < 3; ni++)
        acc[mi][ni] = __builtin_amdgcn_mfma_f32_16x16x32_bf16(a, bfr[ni], acc[mi][ni], 0, 0, 0);
    }
  }
  #pragma unroll
  for (int mi = 0; mi < 4; mi++)
    #pragma unroll
    for (int ni = 0; ni < 3; ni++)
      #pragma unroll
      for (int r = 0; r < 4; r++){
        const int j = j0 + w*64 + mi*16 + (lane >> 4)*4 + r;
        const int d = ni*16 + (lane & 15);
        WmodT[(long)b*589824 + (long)j*768 + h*48 + d] = f2bf(acc[mi][ni][r]);
      }
}

// --- WcombT[6144 rows=b*768+j][768 e] = WmodT[row][hd] @ WvB[e][hd] (128² tile)
__global__ __launch_bounds__(256)
void k_comb(const unsigned short* __restrict__ A, const unsigned short* __restrict__ BT,
            unsigned short* __restrict__ OUT)
{
  __shared__ unsigned short As[128 * 32];
  __shared__ unsigned short Bs[128 * 32];
  const int m0 = blockIdx.y * 128;
  const int j0 = blockIdx.x * 128;
  const int t = threadIdx.x;
  const int lane = t & 63;
  const int w = t >> 6, wm = w >> 1, wn = w & 1;

  f32x4 acc[4][4] = {};

  for (int kt = 0; kt < 768; kt += 32){
    if (kt) __syncthreads();
    #pragma unroll
    for (int i = 0; i < 2; i++){
      const char* ga = (const char*)A  + (long)(m0 + i*64 + (t >> 2)) * 1536 + kt*2 + (t & 3) * 16;
      const char* gb = (const char*)BT + (long)(j0 + i*64 + (t >> 2)) * 1536 + kt*2 + (t & 3) * 16;
      char* la = (char*)As + i*4096 + (t & 0xC0) * 16;
      char* lb = (char*)Bs + i*4096 + (t & 0xC0) * 16;
      GLL(ga, la);
      GLL(gb, lb);
    }
    __syncthreads();
    bf16x8 af[4], bfr[4];
    #pragma unroll
    for (int mi = 0; mi < 4; mi++)
      af[mi]  = *(const bf16x8*)&As[(wm*64 + mi*16 + (lane & 15)) * 32 + (lane >> 4) * 8];
    #pragma unroll
    for (int ni = 0; ni < 4; ni++)
      bfr[ni] = *(const bf16x8*)&Bs[(wn*64 + ni*16 + (lane & 15)) * 32 + (lane >> 4) * 8];
    #pragma unroll
    for (int mi = 0; mi < 4; mi++)
      #pragma unroll
      for (int ni = 0; ni < 4; ni++)
        acc[mi][ni] = __builtin_amdgcn_mfma_f32_16x16x32_bf16(af[mi], bfr[ni], acc[mi][ni], 0, 0, 0);
  }

  #pragma unroll
  for (int mi = 0; mi < 4; mi++)
    #pragma unroll
    for (int ni = 0; ni < 4; ni++){
      const int jc = j0 + wn*64 + ni*16 + (lane & 15);
      const long mr = (long)m0 + wm*64 + mi*16 + (lane >> 4) * 4;
      #pragma unroll
      for (int r = 0; r < 4; r++) OUT[(mr + r) * 768 + jc] = f2bf(acc[mi][ni][r]);
    }
}

extern "C" void kernel_launch(void* const* d_in, const int* in_sizes, int n_in,
                              void* d_out, int out_size, void* d_ws, size_t ws_size,
                              hipStream_t stream)
{
  (void)in_sizes; (void)n_in; (void)out_size; (void)ws_size;
  const float* x      = (const float*)d_in[0];
  const float* w_qkv  = (const float*)d_in[1];
  const float* temp   = (const float*)d_in[2];
  const float* w_proj = (const float*)d_in[3];
  const float* b_proj = (const float*)d_in[4];
  float* outF = (float*)d_out;

  char* ws = (char*)d_ws;
  size_t off = 0;
  auto alloc = [&](size_t bytes)->char*{ char* p = ws + off; off += (bytes + 255) & ~(size_t)255; return p; };

  unsigned short* x_bf  = (unsigned short*)alloc(50331648);           // [32768][768] bf16
  unsigned short* WT    = (unsigned short*)alloc(2359296);            // [1536 q||k][768] bf16
  unsigned short* WpT   = (unsigned short*)alloc(1179648);            // [768][768] bf16
  unsigned short* WvB   = (unsigned short*)alloc(1179648);            // [768 e][768 hd] bf16
  unsigned short* QT    = (unsigned short*)alloc(100663296);          // QT||KT [6144][4096] bf16 each
  unsigned short* KT    = QT + (long)6144 * 4096;
  float* nrmp           = (float*)alloc(12288L * 32 * 4);             // [12288 rows][32 chunks] f32
  float* Spart          = (float*)alloc(4L * 128 * 2304 * 4);         // [4][128][48][48] f32
  unsigned short* attnT = (unsigned short*)alloc(786432);             // [128][48 d][64 c] bf16
  unsigned short* WmodT = (unsigned short*)alloc(9437184);            // [8][768 j][768 hd] bf16
  unsigned short* WcombT= (unsigned short*)alloc(9437184);            // [8][768 j][768 e] bf16

  k_cvt<<<12288, 256, 0, stream>>>(x, x_bf, 25165824L);
  k_tconv<<<dim3(24, 12), 256, 0, stream>>>(w_qkv, WT, 768, 2304);    // q||k cols only
  k_tconv<<<dim3(12, 12), 256, 0, stream>>>(w_proj, WpT, 768, 768);
  k_cvtwv<<<288, 256, 0, stream>>>(w_qkv, WvB);
  k_gemm256<<<768, 512, 0, stream>>>(x_bf, WT, QT, KT, nrmp);
  k_attn_part<<<dim3(128, 4), 256, 0, stream>>>(QT, KT, Spart);
  k_softmax<<<128, 64, 0, stream>>>(Spart, nrmp, temp, attnT);
  k_wmod2<<<dim3(3, 16, 8), 256, 0, stream>>>(WpT, attnT, WmodT);
  k_comb<<<dim3(6, 48), 256, 0, stream>>>(WmodT, WvB, WcombT);
  k_gemmP<<<768, 512, 0, stream>>>(x_bf, WcombT, outF, b_proj);
}

// Round 13
// 238.910 us; speedup vs baseline: 1.1950x; 1.0064x over previous
//
#include <hip/hip_runtime.h>
#include <stdint.h>

typedef __attribute__((ext_vector_type(4))) float          f32x4;
typedef __attribute__((ext_vector_type(8))) short          bf16x8;
typedef __attribute__((ext_vector_type(8))) unsigned short u16x8;
typedef __attribute__((ext_vector_type(4))) unsigned short u16x4;

static __device__ __forceinline__ unsigned short f2bf(float f){
  uint32_t u = __builtin_bit_cast(uint32_t, f);
  u += 0x7FFFu + ((u >> 16) & 1u);          // RNE
  return (unsigned short)(u >> 16);
}
static __device__ __forceinline__ float bf2f(unsigned short h){
  uint32_t u = ((uint32_t)h) << 16;
  return __builtin_bit_cast(float, u);
}

#define GLL(SRC, DST) __builtin_amdgcn_global_load_lds(                         \
    (const __attribute__((address_space(1))) unsigned int*)(SRC),               \
    (__attribute__((address_space(3))) unsigned int*)(DST), 16, 0, 0)

// ---------------- elementwise convert f32 -> bf16 (8/thread) ----------------
__global__ void k_cvt(const float* __restrict__ in, unsigned short* __restrict__ out, long n){
  long i = ((long)blockIdx.x * blockDim.x + threadIdx.x) * 8;
  if (i >= n) return;
  const f32x4* p = (const f32x4*)(in + i);
  f32x4 a = p[0], b = p[1];
  u16x8 o;
  #pragma unroll
  for (int j = 0; j < 4; j++){ o[j] = f2bf(a[j]); o[4+j] = f2bf(b[j]); }
  *(u16x8*)(out + i) = o;
}

// ---------------- tiled transpose+convert: in[R][C] f32 -> out[C][R] bf16 ----
__global__ void k_tconv(const float* __restrict__ in, unsigned short* __restrict__ out, int R, int C){
  __shared__ float tl[64][65];
  const int c0 = blockIdx.x * 64, r0 = blockIdx.y * 64;
  const int t = threadIdx.x;
  {
    const int lr = t >> 2, lc = (t & 3) * 16;
    const f32x4* s = (const f32x4*)(in + (long)(r0 + lr) * C + c0 + lc);
    #pragma unroll
    for (int q = 0; q < 4; q++){
      f32x4 v = s[q];
      #pragma unroll
      for (int j = 0; j < 4; j++) tl[lr][lc + q*4 + j] = v[j];
    }
  }
  __syncthreads();
  {
    const int oc = t >> 2, orr = (t & 3) * 16;
    u16x8 o0, o1;
    #pragma unroll
    for (int i = 0; i < 8; i++){ o0[i] = f2bf(tl[orr + i][oc]); o1[i] = f2bf(tl[orr + 8 + i][oc]); }
    u16x8* dst = (u16x8*)(out + (long)(c0 + oc) * R + r0 + orr);
    dst[0] = o0; dst[1] = o1;
  }
}

// ------- strided cvt: WvB[e][hd] = bf16(w_qkv[e][1536+hd]), 768x768 ---------
__global__ void k_cvtwv(const float* __restrict__ w, unsigned short* __restrict__ out){
  const long idx = ((long)blockIdx.x * blockDim.x + threadIdx.x) * 8;
  const int e = (int)(idx / 768), hd = (int)(idx - (long)e * 768);
  const float* s = w + (long)e * 2304 + 1536 + hd;
  f32x4 a = *(const f32x4*)s, b = *(const f32x4*)(s + 4);
  u16x8 o;
  #pragma unroll
  for (int j = 0; j < 4; j++){ o[j] = f2bf(a[j]); o[4+j] = f2bf(b[j]); }
  *(u16x8*)(out + idx) = o;
}

// ===================== shared fragment read (conflict-free swizzle) =========
// 64B K32 rows; LDS chunk c of row r holds global k-chunk (c ^ ((r>>1)&3)).
// Verified 0 bank conflicts (r10/r11).
static __device__ __forceinline__ bf16x8 ldfrag(const char* slot, int row, int ko){
  const int k2 = (ko ^ (row >> 1)) & 3;
  return *(const bf16x8*)(slot + row*64 + k2*16);
}

// ========== k_gemm256: 256x256 8-phase counted-vmcnt (r11 schedule) =========
// + LDS-transpose coalesced epilogue (this round's single change).
static __device__ __forceinline__ void stg256(const unsigned short* __restrict__ G, int row0, int ke,
                                              char* lds_slot, int t){
  #pragma unroll
  for (int l = 0; l < 2; l++){
    const int r  = l*128 + (t >> 2);
    const int k2 = (t & 3) ^ ((r >> 1) & 3);
    GLL((const char*)(G + (long)(row0 + r) * 768 + ke + k2 * 8),
        lds_slot + l*8192 + (t & 0x1C0) * 16);
  }
}

#define PHASE(BUF, KK, MH, STAGE_STMT, WAIT_STMT) do {                         \
    bf16x8 af[4];                                                              \
    if (MH == 0) {                                                             \
      _Pragma("unroll")                                                        \
      for (int ni = 0; ni < 4; ni++)                                           \
        bq[ni] = ldfrag(sB[BUF][KK], wn*64 + ni*16 + arow, ko);                \
    }                                                                          \
    _Pragma("unroll")                                                          \
    for (int mi = 0; mi < 4; mi++)                                             \
      af[mi] = ldfrag(sA[BUF][KK], wm*128 + MH*64 + mi*16 + arow, ko);         \
    __builtin_amdgcn_s_barrier();                                              \
    __builtin_amdgcn_s_setprio(1);                                             \
    _Pragma("unroll")                                                          \
    for (int mi = 0; mi < 4; mi++)                                             \
      _Pragma("unroll")                                                        \
      for (int ni = 0; ni < 4; ni++)                                           \
        acc[MH*4+mi][ni] = __builtin_amdgcn_mfma_f32_16x16x32_bf16(            \
            af[mi], bq[ni], acc[MH*4+mi][ni], 0, 0, 0);                        \
    __builtin_amdgcn_s_setprio(0);                                             \
    STAGE_STMT;                                                                \
    WAIT_STMT;                                                                 \
    __builtin_amdgcn_s_barrier();                                              \
  } while(0)

// A=x_bf[32768][768], BT=WT[1536 q||k][768] -> QT/KT (transposed) + nrmp
__global__ __launch_bounds__(512, 2)
void k_gemm256(const unsigned short* __restrict__ A, const unsigned short* __restrict__ BT,
               unsigned short* __restrict__ QT, unsigned short* __restrict__ KT,
               float* __restrict__ nrmp)
{
  __shared__ __attribute__((aligned(16))) char lds[131072];
  const int o  = blockIdx.x;
  const int wg = (o & 7) * 96 + (o >> 3);          // bijective XCD swizzle, 768 wgs
  const int jt = wg % 6, mt = wg / 6;
  const int m0 = mt * 256, j0 = jt * 256;
  const int t = threadIdx.x, lane = t & 63, w = t >> 6;
  const int wm = w >> 2, wn = w & 3;
  const int arow = lane & 15, ko = lane >> 4;

  char* const sA[2][2] = {{lds,           lds + 16384},
                          {lds + 65536,   lds + 65536 + 16384}};
  char* const sB[2][2] = {{lds + 32768,   lds + 49152},
                          {lds + 65536 + 32768, lds + 65536 + 49152}};

  f32x4 acc[8][4] = {};

  // prologue: tile0 fully; tile1 all but A1 (staged at iter0-ph1)
  stg256(BT, j0, 0,   sB[0][0], t);
  stg256(A,  m0, 0,   sA[0][0], t);
  stg256(BT, j0, 32,  sB[0][1], t);
  stg256(A,  m0, 32,  sA[0][1], t);
  stg256(BT, j0, 64,  sB[1][0], t);
  stg256(A,  m0, 64,  sA[1][0], t);
  stg256(BT, j0, 96,  sB[1][1], t);
  asm volatile("s_waitcnt vmcnt(6)" ::: "memory");
  __builtin_amdgcn_s_barrier();

  #pragma unroll 1
  for (int it = 0; it < 6; ++it){
    const int t1 = 2*it + 1, t2 = 2*it + 2, t3 = 2*it + 3;
    bf16x8 bq[4];
    // ---- tile T0 = 2*it (buf0) ----
    PHASE(0,0,0, { stg256(A, m0, t1*64+32, sA[1][1], t); }, ;);                  // A1(T1)
    PHASE(0,0,1, { if (t2 < 12) stg256(BT, j0, t2*64,    sB[0][0], t); }, ;);    // B0(T2)
    PHASE(0,1,0, { if (t2 < 12) stg256(A,  m0, t2*64,    sA[0][0], t); }, ;);    // A0(T2)
    PHASE(0,1,1, { if (t2 < 12) stg256(BT, j0, t2*64+32, sB[0][1], t); },
                 { if (it == 5) asm volatile("s_waitcnt vmcnt(0)" ::: "memory");
                   else         asm volatile("s_waitcnt vmcnt(6)" ::: "memory"); });
    // ---- tile T1 (buf1) ----
    PHASE(1,0,0, { if (t2 < 12) stg256(A,  m0, t2*64+32, sA[0][1], t); }, ;);    // A1(T2)
    PHASE(1,0,1, { if (t3 < 12) stg256(BT, j0, t3*64,    sB[1][0], t); }, ;);    // B0(T3)
    PHASE(1,1,0, { if (t3 < 12) stg256(A,  m0, t3*64,    sA[1][0], t); }, ;);    // A0(T3)
    PHASE(1,1,1, { if (t3 < 12) stg256(BT, j0, t3*64+32, sB[1][1], t); },
                 { if (it == 5) asm volatile("s_waitcnt vmcnt(0)" ::: "memory");
                   else         asm volatile("s_waitcnt vmcnt(6)" ::: "memory"); });
  }

  const int b = m0 >> 12;
  // (1) nrmp: per-(row, 128-chunk) sum-of-squares partials (fp32, pre-bf16)
  const int chunk = ((m0 & 4095) >> 7) + wm;   // 32 chunks of 128 per batch-row
  #pragma unroll
  for (int ni = 0; ni < 4; ni++){
    float ss = 0.f;
    #pragma unroll
    for (int mi = 0; mi < 8; mi++)
      #pragma unroll
      for (int r = 0; r < 4; r++) ss += acc[mi][ni][r] * acc[mi][ni][r];
    ss += __shfl_xor(ss, 16);
    ss += __shfl_xor(ss, 32);
    if (lane < 16){
      const int jc = j0 + wn*64 + ni*16 + lane;
      const int s  = (jc >= 768);
      const int jl = jc - s * 768;
      const int h  = jl / 48;
      const int c  = jl - h * 48;
      nrmp[(long)(s*6144 + (b*16 + h)*48 + c)*32 + chunk] = ss;
    }
  }
  // (2) dump acc -> LDS bf16 T[256 j][256 n] (512B rows); 8B-slot XOR swizzle
  //     slot' = slot ^ (j&7)  -> <=2-way banks on write, 2-way (free) on read.
  //     Safe to reuse lds: last gate was vmcnt(0), final phase barrier passed.
  #pragma unroll
  for (int mi = 0; mi < 8; mi++){
    #pragma unroll
    for (int ni = 0; ni < 4; ni++){
      const int j   = wn*64 + ni*16 + (lane & 15);
      const int nb8 = (wm*128 + mi*16 + (lane >> 4)*4) * 2;   // byte offset in row
      u16x4 pk;
      #pragma unroll
      for (int r = 0; r < 4; r++) pk[r] = f2bf(acc[mi][ni][r]);
      *(u16x4*)(lds + (long)j*512 + (((nb8 >> 3) ^ (j & 7)) << 3)) = pk;
    }
  }
  __syncthreads();
  // (3) coalesced store: each wave stores 32 rows, 512B contiguous per row
  for (int rr = 0; rr < 32; rr++){
    const int j  = w*32 + rr;
    const int jc = j0 + j;
    const int s  = (jc >= 768);
    const int jl = jc - s * 768;
    const int h  = jl / 48;
    const int c  = jl - h * 48;
    uint2 v = *(const uint2*)(lds + (long)j*512 + ((lane ^ (j & 7)) << 3));
    *(uint2*)((s ? KT : QT) + (((long)(b*16 + h) * 48 + c) << 12) + (m0 & 4095) + lane*4) = v;
  }
}

// ===== k_gemmP: 128x256 BK=32 ring-3 (r9-proven), x_bf @ WcombT_b -> outF ===
static __device__ __forceinline__ void stageA512(const unsigned short* __restrict__ G, int row0, int ke,
                                                 char* slot, int t){
  const int r  = t >> 2;
  const int k2 = (t & 3) ^ ((r >> 1) & 3);
  GLL((const char*)(G + (long)(row0 + r) * 768 + ke + k2 * 8), slot + (t & 0x1C0) * 16);
}
static __device__ __forceinline__ void stageB512(const unsigned short* __restrict__ G, int row0, int ke,
                                                 char* slot, int t){
  #pragma unroll
  for (int l = 0; l < 2; l++){
    const int r  = l*128 + (t >> 2);
    const int k2 = (t & 3) ^ ((r >> 1) & 3);
    GLL((const char*)(G + (long)(row0 + r) * 768 + ke + k2 * 8), slot + l*8192 + (t & 0x1C0) * 16);
  }
}

#define VM0 asm volatile("s_waitcnt vmcnt(0)" ::: "memory")
#define VM3 asm volatile("s_waitcnt vmcnt(3)" ::: "memory")

#define PHASE1(CUR, STAGE_STMT, WAIT_STMT) do {                                \
    bf16x8 af[4], bq[4];                                                       \
    _Pragma("unroll")                                                          \
    for (int ni = 0; ni < 4; ni++)                                             \
      bq[ni] = ldfrag(sB[CUR], wn*64 + ni*16 + arow, ko);                      \
    _Pragma("unroll")                                                          \
    for (int mi = 0; mi < 4; mi++)                                             \
      af[mi] = ldfrag(sA[CUR], wm64 + mi*16 + arow, ko);                       \
    __builtin_amdgcn_s_barrier();                                              \
    __builtin_amdgcn_s_setprio(1);                                             \
    _Pragma("unroll")                                                          \
    for (int mi = 0; mi < 4; mi++)                                             \
      _Pragma("unroll")                                                        \
      for (int ni = 0; ni < 4; ni++)                                           \
        acc[mi][ni] = __builtin_amdgcn_mfma_f32_16x16x32_bf16(                 \
            af[mi], bq[ni], acc[mi][ni], 0, 0, 0);                             \
    __builtin_amdgcn_s_setprio(0);                                             \
    STAGE_STMT;                                                                \
    WAIT_STMT;                                                                 \
    __builtin_amdgcn_s_barrier();                                              \
  } while(0)

__global__ __launch_bounds__(512, 4)
void k_gemmP(const unsigned short* __restrict__ A, const unsigned short* __restrict__ BT,
             float* __restrict__ OUTF, const float* __restrict__ bias)
{
  __shared__ __attribute__((aligned(16))) char lds[73728];
  const int o  = blockIdx.x;
  const int wg = (o & 7) * 96 + (o >> 3);                  // 768 wgs
  const int jt = wg % 3, mt = wg / 3;
  const int m0 = mt * 128, j0 = jt * 256;
  const int t = threadIdx.x, lane = t & 63, w = t >> 6;
  const int wm = w >> 2, wn = w & 3;
  const int wm64 = wm * 64;
  const int arow = lane & 15, ko = lane >> 4;
  const unsigned short* BTb = BT + ((long)(m0 >> 12)) * 589824;

  char* const sA[3] = {lds,          lds + 8192,          lds + 16384};
  char* const sB[3] = {lds + 24576,  lds + 24576 + 16384, lds + 24576 + 32768};

  f32x4 acc[4][4] = {};

  stageA512(A, m0, 0,  sA[0], t);  stageB512(BTb, j0, 0,  sB[0], t);
  stageA512(A, m0, 32, sA[1], t);  stageB512(BTb, j0, 32, sB[1], t);
  VM3;
  __builtin_amdgcn_s_barrier();

  #pragma unroll 1
  for (int g = 0; g < 7; ++g){
    const int kb = g * 96;
    PHASE1(0, { stageA512(A, m0, kb+64,  sA[2], t); stageB512(BTb, j0, kb+64,  sB[2], t); }, VM3);
    PHASE1(1, { stageA512(A, m0, kb+96,  sA[0], t); stageB512(BTb, j0, kb+96,  sB[0], t); }, VM3);
    PHASE1(2, { stageA512(A, m0, kb+128, sA[1], t); stageB512(BTb, j0, kb+128, sB[1], t); }, VM3);
  }
  PHASE1(0, { stageA512(A, m0, 736, sA[2], t); stageB512(BTb, j0, 736, sB[2], t); }, VM3);
  PHASE1(1, { ; }, VM0);
  PHASE1(2, { ; }, ;);

  #pragma unroll
  for (int mi = 0; mi < 4; mi++){
    #pragma unroll
    for (int ni = 0; ni < 4; ni++){
      const int jc = j0 + wn*64 + ni*16 + (lane & 15);
      const float bv = bias[jc];
      const long mr = (long)m0 + wm64 + mi*16 + (lane >> 4)*4;
      #pragma unroll
      for (int r = 0; r < 4; r++) OUTF[(mr + r) * 768 + jc] = acc[mi][ni][r] + bv;
    }
  }
}

// ---------------- S partials: per (bh, ksp) 48x48 over 1024 n ---------------
__global__ __launch_bounds__(256)
void k_attn_part(const unsigned short* __restrict__ QT, const unsigned short* __restrict__ KT,
                 float* __restrict__ Spart)
{
  __shared__ float Sl[4][2304];
  const int bh = blockIdx.x, ksp = blockIdx.y;
  const int t = threadIdx.x, lane = t & 63, w = t >> 6;
  const unsigned short* qb = QT + ((long)bh * 48 << 12);
  const unsigned short* kb = KT + ((long)bh * 48 << 12);
  const int n00 = ksp * 1024 + w * 256;
  f32x4 acc[3][3] = {};
  for (int kt = 0; kt < 256; kt += 32){
    bf16x8 af[3], bfr[3];
    #pragma unroll
    for (int ci = 0; ci < 3; ci++)
      af[ci]  = *(const bf16x8*)(qb + ((long)(ci*16 + (lane & 15)) << 12) + n00 + kt + (lane >> 4) * 8);
    #pragma unroll
    for (int di = 0; di < 3; di++)
      bfr[di] = *(const bf16x8*)(kb + ((long)(di*16 + (lane & 15)) << 12) + n00 + kt + (lane >> 4) * 8);
    #pragma unroll
    for (int ci = 0; ci < 3; ci++)
      #pragma unroll
      for (int di = 0; di < 3; di++)
        acc[ci][di] = __builtin_amdgcn_mfma_f32_16x16x32_bf16(af[ci], bfr[di], acc[ci][di], 0, 0, 0);
  }
  #pragma unroll
  for (int ci = 0; ci < 3; ci++)
    #pragma unroll
    for (int di = 0; di < 3; di++)
      #pragma unroll
      for (int r = 0; r < 4; r++)
        Sl[w][(ci*16 + (lane >> 4)*4 + r) * 48 + di*16 + (lane & 15)] = acc[ci][di][r];
  __syncthreads();
  float* outp = Spart + ((long)ksp * 128 + bh) * 2304;
  for (int idx = t; idx < 2304; idx += 256)
    outp[idx] = Sl[0][idx] + Sl[1][idx] + Sl[2][idx] + Sl[3][idx];
}

// --- reduce partials + norms, scale, softmax -> attnT bf16 [bh][48 d][64 c] --
__global__ void k_softmax(const float* __restrict__ Spart, const float* __restrict__ nrmp,
                          const float* __restrict__ temp, unsigned short* __restrict__ attnT)
{
  __shared__ float invq[48], invk[48];
  const int bh = blockIdx.x, h = bh & 15;
  const int c = threadIdx.x;   // 64 threads, 48 active
  if (c < 48){
    float sq = 0.f, sk = 0.f;
    const float* pq = nrmp + (long)(bh*48 + c) * 32;
    const float* pk = nrmp + (long)(6144 + bh*48 + c) * 32;
    #pragma unroll
    for (int i = 0; i < 32; i++){ sq += pq[i]; sk += pk[i]; }
    invq[c] = 1.0f / fmaxf(sqrtf(sq), 1e-12f);
    invk[c] = 1.0f / fmaxf(sqrtf(sk), 1e-12f);
  }
  __syncthreads();
  if (c < 48){
    const float scq = invq[c] * temp[h];
    float row[48];
    #pragma unroll
    for (int d = 0; d < 48; d++){
      long base = ((long)bh * 48 + c) * 48 + d;
      float v = Spart[base] + Spart[base + 128L*2304] + Spart[base + 256L*2304] + Spart[base + 384L*2304];
      row[d] = v * scq * invk[d];
    }
    float mx = -1e30f;
    #pragma unroll
    for (int d = 0; d < 48; d++) mx = fmaxf(mx, row[d]);
    float s = 0.f;
    #pragma unroll
    for (int d = 0; d < 48; d++){ row[d] = expf(row[d] - mx); s += row[d]; }
    const float inv = 1.0f / s;
    unsigned short* ob = attnT + (long)bh * 48 * 64;
    #pragma unroll
    for (int d = 0; d < 48; d++) ob[d*64 + c] = f2bf(row[d] * inv);
    u16x8 z = {};
    *(u16x8*)(ob + c*64 + 48) = z;
    *(u16x8*)(ob + c*64 + 56) = z;
  }
}

// --- WmodT[b][j][h*48+d] = sum_c attnT[bh][d][c] * WpT[j][h*48+c] (MFMA) -----
__global__ __launch_bounds__(256)
void k_wmod2(const unsigned short* __restrict__ WpT, const unsigned short* __restrict__ attnT,
             unsigned short* __restrict__ WmodT)
{
  const int j0 = blockIdx.x * 256, h = blockIdx.y, b = blockIdx.z;
  const int t = threadIdx.x, lane = t & 63, w = t >> 6;
  const unsigned short* wp = WpT + h * 48;
  const unsigned short* ab = attnT + ((long)(b*16 + h)) * 48 * 64;
  f32x4 acc[4][3] = {};
  #pragma unroll
  for (int kt = 0; kt < 64; kt += 32){
    bf16x8 bfr[3];
    #pragma unroll
    for (int ni = 0; ni < 3; ni++)
      bfr[ni] = *(const bf16x8*)(ab + (ni*16 + (lane & 15))*64 + kt + (lane >> 4)*8);
    #pragma unroll
    for (int mi = 0; mi < 4; mi++){
      const int j = j0 + w*64 + mi*16 + (lane & 15);
      bf16x8 a = *(const bf16x8*)(wp + (long)j*768 + kt + (lane >> 4)*8);
      #pragma unroll
      for (int ni = 0; ni < 3; ni++)
        acc[mi][ni] = __builtin_amdgcn_mfma_f32_16x16x32_bf16(a, bfr[ni], acc[mi][ni], 0, 0, 0);
    }
  }
  #pragma unroll
  for (int mi = 0; mi < 4; mi++)
    #pragma unroll
    for (int ni = 0; ni < 3; ni++)
      #pragma unroll
      for (int r = 0; r < 4; r++){
        const int j = j0 + w*64 + mi*16 + (lane >> 4)*4 + r;
        const int d = ni*16 + (lane & 15);
        WmodT[(long)b*589824 + (long)j*768 + h*48 + d] = f2bf(acc[mi][ni][r]);
      }
}

// --- WcombT[6144 rows=b*768+j][768 e] = WmodT[row][hd] @ WvB[e][hd] (128² tile)
__global__ __launch_bounds__(256)
void k_comb(const unsigned short* __restrict__ A, const unsigned short* __restrict__ BT,
            unsigned short* __restrict__ OUT)
{
  __shared__ unsigned short As[128 * 32];
  __shared__ unsigned short Bs[128 * 32];
  const int m0 = blockIdx.y * 128;
  const int j0 = blockIdx.x * 128;
  const int t = threadIdx.x;
  const int lane = t & 63;
  const int w = t >> 6, wm = w >> 1, wn = w & 1;

  f32x4 acc[4][4] = {};

  for (int kt = 0; kt < 768; kt += 32){
    if (kt) __syncthreads();
    #pragma unroll
    for (int i = 0; i < 2; i++){
      const char* ga = (const char*)A  + (long)(m0 + i*64 + (t >> 2)) * 1536 + kt*2 + (t & 3) * 16;
      const char* gb = (const char*)BT + (long)(j0 + i*64 + (t >> 2)) * 1536 + kt*2 + (t & 3) * 16;
      char* la = (char*)As + i*4096 + (t & 0xC0) * 16;
      char* lb = (char*)Bs + i*4096 + (t & 0xC0) * 16;
      GLL(ga, la);
      GLL(gb, lb);
    }
    __syncthreads();
    bf16x8 af[4], bfr[4];
    #pragma unroll
    for (int mi = 0; mi < 4; mi++)
      af[mi]  = *(const bf16x8*)&As[(wm*64 + mi*16 + (lane & 15)) * 32 + (lane >> 4) * 8];
    #pragma unroll
    for (int ni = 0; ni < 4; ni++)
      bfr[ni] = *(const bf16x8*)&Bs[(wn*64 + ni*16 + (lane & 15)) * 32 + (lane >> 4) * 8];
    #pragma unroll
    for (int mi = 0; mi < 4; mi++)
      #pragma unroll
      for (int ni = 0; ni < 4; ni++)
        acc[mi][ni] = __builtin_amdgcn_mfma_f32_16x16x32_bf16(af[mi], bfr[ni], acc[mi][ni], 0, 0, 0);
  }

  #pragma unroll
  for (int mi = 0; mi < 4; mi++)
    #pragma unroll
    for (int ni = 0; ni < 4; ni++){
      const int jc = j0 + wn*64 + ni*16 + (lane & 15);
      const long mr = (long)m0 + wm*64 + mi*16 + (lane >> 4) * 4;
      #pragma unroll
      for (int r = 0; r < 4; r++) OUT[(mr + r) * 768 + jc] = f2bf(acc[mi][ni][r]);
    }
}

extern "C" void kernel_launch(void* const* d_in, const int* in_sizes, int n_in,
                              void* d_out, int out_size, void* d_ws, size_t ws_size,
                              hipStream_t stream)
{
  (void)in_sizes; (void)n_in; (void)out_size; (void)ws_size;
  const float* x      = (const float*)d_in[0];
  const float* w_qkv  = (const float*)d_in[1];
  const float* temp   = (const float*)d_in[2];
  const float* w_proj = (const float*)d_in[3];
  const float* b_proj = (const float*)d_in[4];
  float* outF = (float*)d_out;

  char* ws = (char*)d_ws;
  size_t off = 0;
  auto alloc = [&](size_t bytes)->char*{ char* p = ws + off; off += (bytes + 255) & ~(size_t)255; return p; };

  unsigned short* x_bf  = (unsigned short*)alloc(50331648);           // [32768][768] bf16
  unsigned short* WT    = (unsigned short*)alloc(2359296);            // [1536 q||k][768] bf16
  unsigned short* WpT   = (unsigned short*)alloc(1179648);            // [768][768] bf16
  unsigned short* WvB   = (unsigned short*)alloc(1179648);            // [768 e][768 hd] bf16
  unsigned short* QT    = (unsigned short*)alloc(100663296);          // QT||KT [6144][4096] bf16 each
  unsigned short* KT    = QT + (long)6144 * 4096;
  float* nrmp           = (float*)alloc(12288L * 32 * 4);             // [12288 rows][32 chunks] f32
  float* Spart          = (float*)alloc(4L * 128 * 2304 * 4);         // [4][128][48][48] f32
  unsigned short* attnT = (unsigned short*)alloc(786432);             // [128][48 d][64 c] bf16
  unsigned short* WmodT = (unsigned short*)alloc(9437184);            // [8][768 j][768 hd] bf16
  unsigned short* WcombT= (unsigned short*)alloc(9437184);            // [8][768 j][768 e] bf16

  k_cvt<<<12288, 256, 0, stream>>>(x, x_bf, 25165824L);
  k_tconv<<<dim3(24, 12), 256, 0, stream>>>(w_qkv, WT, 768, 2304);    // q||k cols only
  k_tconv<<<dim3(12, 12), 256, 0, stream>>>(w_proj, WpT, 768, 768);
  k_cvtwv<<<288, 256, 0, stream>>>(w_qkv, WvB);
  k_gemm256<<<768, 512, 0, stream>>>(x_bf, WT, QT, KT, nrmp);
  k_attn_part<<<dim3(128, 4), 256, 0, stream>>>(QT, KT, Spart);
  k_softmax<<<128, 64, 0, stream>>>(Spart, nrmp, temp, attnT);
  k_wmod2<<<dim3(3, 16, 8), 256, 0, stream>>>(WpT, attnT, WmodT);
  k_comb<<<dim3(6, 48), 256, 0, stream>>>(WmodT, WvB, WcombT);
  k_gemmP<<<768, 512, 0, stream>>>(x_bf, WcombT, outF, b_proj);
}